// Round 15
// baseline (1458.344 us; speedup 1.0000x reference)
//
#include <hip/hip_runtime.h>
#include <math.h>

// ---------------- problem constants ----------------
constexpr int cNB = 50000, cNBV = 100000, cNLT = 10000, cNC = 2000, cNT = 115;
constexpr int cEV = 400000, cER = 50000, cNVOTE = 100000;
constexpr int cNTOT = cNB + cNBV + cNLT + cNC + cNT;   // 162115
constexpr int cLAYERS = 3;
constexpr int F9TOT = 362115;   // sum of n_dst over 8 relations
constexpr int ETOT  = 1200000;  // sum of E over 8 relations
constexpr int LS = 40;          // LDS row stride (BK=32 kernels)
constexpr int LS2 = 72;         // LDS row stride (BK=64 kernels): 144B = 9*16B

typedef __attribute__((ext_vector_type(8))) short bf16x8;
typedef __attribute__((ext_vector_type(4))) float f32x4;
union pack8 { uint4 u; bf16x8 v; };

__device__ __forceinline__ ushort f2b(float f) {
  union { float f; uint u; } v; v.f = f;
  uint r = v.u + 0x7fffu + ((v.u >> 16) & 1u);   // RNE
  return (ushort)(r >> 16);
}
__device__ __forceinline__ float b2f(ushort b) {
  union { uint u; float f; } v; v.u = ((uint)b) << 16; return v.f;
}

// ====== fused SAGE GEMM + LN epilogue: 64-row tile, BK=64, wave = 16x128 strip ======
struct SageG {
  const ushort* A[5][4];
  const ushort* Wt[5];
  const float* bias[5];
  const float* lng[5];
  const float* lnb[5];
  ushort* C[5];
  int M[5];
  int Ktot[5];
  int blkStart[6];
};

__global__ __launch_bounds__(256)
void gemm_sage(SageG sg)
{
  __shared__ ushort As[64 * LS2];
  __shared__ ushort Bs[128 * LS2];
  const int bid = blockIdx.x;
  int t = 0;
  while (bid >= sg.blkStart[t + 1]) ++t;
  const int row0 = (bid - sg.blkStart[t]) << 6;
  const int M = sg.M[t], Ktot = sg.Ktot[t];
  const ushort* Wt = sg.Wt[t];
  const int tid = threadIdx.x;
  const int l = tid & 63, wid = tid >> 6;
  const int lr = l & 15, lkh = l >> 4;
  const int ar2 = tid >> 2, aq2 = tid & 3;   // A staging: 64 rows x chunks {aq2, aq2+4}
  const int br2 = tid >> 1, bh2 = tid & 1;   // B staging: 128 rows x 4 chunks

  f32x4 acc[8];
#pragma unroll
  for (int n = 0; n < 8; ++n) acc[n] = (f32x4)0.f;

  uint4 pa0, pa1, pb[4];
  auto loadAB = [&](int kk) {
    const ushort* Ap = sg.A[t][kk >> 7];
    const int k0 = kk & 127;
    const int gr = row0 + ar2;
    pa0 = make_uint4(0, 0, 0, 0);
    pa1 = make_uint4(0, 0, 0, 0);
    if (gr < M) {
      pa0 = *(const uint4*)(Ap + (size_t)gr * 128 + k0 + aq2 * 8);
      pa1 = *(const uint4*)(Ap + (size_t)gr * 128 + k0 + (aq2 + 4) * 8);
    }
    const ushort* bp = Wt + (size_t)br2 * Ktot + kk + bh2 * 32;
#pragma unroll
    for (int j = 0; j < 4; ++j) pb[j] = *(const uint4*)(bp + j * 8);
  };

  loadAB(0);
  for (int kk = 0; kk < Ktot; kk += 64) {
    *(uint4*)&As[ar2 * LS2 + aq2 * 8] = pa0;
    *(uint4*)&As[ar2 * LS2 + (aq2 + 4) * 8] = pa1;
#pragma unroll
    for (int j = 0; j < 4; ++j)
      *(uint4*)&Bs[br2 * LS2 + (bh2 * 4 + j) * 8] = pb[j];
    __syncthreads();
    if (kk + 64 < Ktot) loadAB(kk + 64);
#pragma unroll
    for (int ks = 0; ks < 2; ++ks) {
      const bf16x8 af = *(const bf16x8*)&As[(wid * 16 + lr) * LS2 + ks * 32 + lkh * 8];
      bf16x8 bfv[8];
#pragma unroll
      for (int n = 0; n < 8; ++n)
        bfv[n] = *(const bf16x8*)&Bs[(n * 16 + lr) * LS2 + ks * 32 + lkh * 8];
#pragma unroll
      for (int n = 0; n < 8; ++n)
        acc[n] = __builtin_amdgcn_mfma_f32_16x16x32_bf16(af, bfv[n], acc[n], 0, 0, 0);
    }
    __syncthreads();
  }

  const float* bias = sg.bias[t];
  const float* g = sg.lng[t];
  const float* bb = sg.lnb[t];
  ushort* C = sg.C[t];
  const int rbase = row0 + wid * 16 + lkh * 4;
  float bi[8], gv[8], bv[8];
#pragma unroll
  for (int n = 0; n < 8; ++n) {
    const int col = n * 16 + lr;
    bi[n] = bias[col]; gv[n] = g[col]; bv[n] = bb[col];
  }
#pragma unroll
  for (int j = 0; j < 4; ++j) {
    const int gr = rbase + j;
    float x[8];
    float s = 0.f;
#pragma unroll
    for (int n = 0; n < 8; ++n) { x[n] = acc[n][j] + bi[n]; s += x[n]; }
#pragma unroll
    for (int m = 1; m < 16; m <<= 1) s += __shfl_xor(s, m);
    const float mean = s * (1.f / 128.f);
    float v = 0.f;
#pragma unroll
    for (int n = 0; n < 8; ++n) { const float d = x[n] - mean; v += d * d; }
#pragma unroll
    for (int m = 1; m < 16; m <<= 1) v += __shfl_xor(v, m);
    const float rinv = rsqrtf(v * (1.f / 128.f) + 1e-5f);
    if (gr < M) {
#pragma unroll
      for (int n = 0; n < 8; ++n) {
        const int col = n * 16 + lr;
        C[(size_t)gr * 128 + col] = f2b((x[n] - mean) * rinv * gv[n] + bv[n]);
      }
    }
  }
}

// ============ bf16 MFMA GEMM (head): up to 4 segments, generic N, reg-prefetch ============
template<int NSEG, bool RELU>
__global__ __launch_bounds__(256)
void gemm_abf(const ushort* __restrict__ A0, const ushort* __restrict__ A1,
              const ushort* __restrict__ A2, const ushort* __restrict__ A3,
              int Astride, const ushort* __restrict__ Wt, int Ktot,
              const float* __restrict__ bias, ushort* __restrict__ C,
              int Cstride, int M)
{
  __shared__ ushort As[128 * LS];
  __shared__ ushort Bs[128 * LS];
  const int tid = threadIdx.x;
  const int row0 = blockIdx.y << 7;
  const int col0 = blockIdx.x << 7;
  const int l = tid & 63, wid = tid >> 6;
  const int wr = wid >> 1, wc = wid & 1;
  const int lr = l & 15, lkh = l >> 4;
  const int srow = tid >> 2, sq = tid & 3;

  f32x4 acc[4][4];
#pragma unroll
  for (int m = 0; m < 4; ++m)
#pragma unroll
    for (int n = 0; n < 4; ++n) acc[m][n] = (f32x4)0.f;

  const int KT2 = NSEG * 128;
  uint4 pa0, pa1, pb0, pb1;
  auto loadAB = [&](int kk) {
    const int ks = kk >> 7;
    const ushort* Ap = (ks == 0) ? A0 : (ks == 1) ? A1 : (ks == 2) ? A2 : A3;
    const int k0 = kk & 127;
    {
      const int gr = row0 + srow;
      pa0 = make_uint4(0, 0, 0, 0);
      if (gr < M) pa0 = *(const uint4*)(Ap + (size_t)gr * Astride + k0 + sq * 8);
      pb0 = *(const uint4*)(Wt + (size_t)(col0 + srow) * Ktot + kk + sq * 8);
    }
    {
      const int gr = row0 + srow + 64;
      pa1 = make_uint4(0, 0, 0, 0);
      if (gr < M) pa1 = *(const uint4*)(Ap + (size_t)gr * Astride + k0 + sq * 8);
      pb1 = *(const uint4*)(Wt + (size_t)(col0 + srow + 64) * Ktot + kk + sq * 8);
    }
  };

  loadAB(0);
  for (int kk = 0; kk < KT2; kk += 32) {
    *(uint4*)&As[srow * LS + sq * 8] = pa0;
    *(uint4*)&As[(srow + 64) * LS + sq * 8] = pa1;
    *(uint4*)&Bs[srow * LS + sq * 8] = pb0;
    *(uint4*)&Bs[(srow + 64) * LS + sq * 8] = pb1;
    __syncthreads();
    if (kk + 32 < KT2) loadAB(kk + 32);
    bf16x8 af[4], bf[4];
#pragma unroll
    for (int m = 0; m < 4; ++m)
      af[m] = *(const bf16x8*)&As[(wr * 64 + m * 16 + lr) * LS + lkh * 8];
#pragma unroll
    for (int n = 0; n < 4; ++n)
      bf[n] = *(const bf16x8*)&Bs[(wc * 64 + n * 16 + lr) * LS + lkh * 8];
#pragma unroll
    for (int m = 0; m < 4; ++m)
#pragma unroll
      for (int n = 0; n < 4; ++n)
        acc[m][n] = __builtin_amdgcn_mfma_f32_16x16x32_bf16(af[m], bf[n], acc[m][n], 0, 0, 0);
    __syncthreads();
  }

#pragma unroll
  for (int n = 0; n < 4; ++n) {
    const int col = col0 + wc * 64 + n * 16 + lr;
    const float bi = bias[col];
#pragma unroll
    for (int m = 0; m < 4; ++m) {
      const f32x4 v = acc[m][n];
      const int rbase = row0 + wr * 64 + m * 16 + lkh * 4;
#pragma unroll
      for (int j = 0; j < 4; ++j) {
        const int gr = rbase + j;
        if (gr < M) {
          float x = v[j] + bi;
          if (RELU) x = fmaxf(x, 0.f);
          C[(size_t)gr * Cstride + col] = f2b(x);
        }
      }
    }
  }
}

// ============ gather-GEMM: 4 segments with per-row index arrays, reg-prefetch ============
template<bool RELU>
__global__ __launch_bounds__(256)
void gemm_gat4(const ushort* __restrict__ A0, const int* __restrict__ i0,
               const ushort* __restrict__ A1, const int* __restrict__ i1,
               const ushort* __restrict__ A2, const int* __restrict__ i2,
               const ushort* __restrict__ A3,
               const ushort* __restrict__ Wt, const float* __restrict__ bias,
               ushort* __restrict__ C, int Cstride, int M)
{
  __shared__ ushort As[128 * LS];
  __shared__ ushort Bs[128 * LS];
  const int tid = threadIdx.x;
  const int row0 = blockIdx.y << 7;
  const int col0 = blockIdx.x << 7;
  const int l = tid & 63, wid = tid >> 6;
  const int wr = wid >> 1, wc = wid & 1;
  const int lr = l & 15, lkh = l >> 4;
  const int srow = tid >> 2, sq = tid & 3;

  f32x4 acc[4][4];
#pragma unroll
  for (int m = 0; m < 4; ++m)
#pragma unroll
    for (int n = 0; n < 4; ++n) acc[m][n] = (f32x4)0.f;

  uint4 pa0, pa1, pb0, pb1;
  auto loadAB = [&](int kk) {
    const int ks = kk >> 7;
    const ushort* Ap = (ks == 0) ? A0 : (ks == 1) ? A1 : (ks == 2) ? A2 : A3;
    const int* ip = (ks == 0) ? i0 : (ks == 1) ? i1 : (ks == 2) ? i2 : nullptr;
    const int k0 = kk & 127;
    {
      const int gr = row0 + srow;
      pa0 = make_uint4(0, 0, 0, 0);
      if (gr < M) {
        const int ar = ip ? ip[gr] : gr;
        pa0 = *(const uint4*)(Ap + (size_t)ar * 128 + k0 + sq * 8);
      }
      pb0 = *(const uint4*)(Wt + (size_t)(col0 + srow) * 512 + kk + sq * 8);
    }
    {
      const int gr = row0 + srow + 64;
      pa1 = make_uint4(0, 0, 0, 0);
      if (gr < M) {
        const int ar = ip ? ip[gr] : gr;
        pa1 = *(const uint4*)(Ap + (size_t)ar * 128 + k0 + sq * 8);
      }
      pb1 = *(const uint4*)(Wt + (size_t)(col0 + srow + 64) * 512 + kk + sq * 8);
    }
  };

  loadAB(0);
  for (int kk = 0; kk < 512; kk += 32) {
    *(uint4*)&As[srow * LS + sq * 8] = pa0;
    *(uint4*)&As[(srow + 64) * LS + sq * 8] = pa1;
    *(uint4*)&Bs[srow * LS + sq * 8] = pb0;
    *(uint4*)&Bs[(srow + 64) * LS + sq * 8] = pb1;
    __syncthreads();
    if (kk + 32 < 512) loadAB(kk + 32);
    bf16x8 af[4], bf[4];
#pragma unroll
    for (int m = 0; m < 4; ++m)
      af[m] = *(const bf16x8*)&As[(wr * 64 + m * 16 + lr) * LS + lkh * 8];
#pragma unroll
    for (int n = 0; n < 4; ++n)
      bf[n] = *(const bf16x8*)&Bs[(wc * 64 + n * 16 + lr) * LS + lkh * 8];
#pragma unroll
    for (int m = 0; m < 4; ++m)
#pragma unroll
      for (int n = 0; n < 4; ++n)
        acc[m][n] = __builtin_amdgcn_mfma_f32_16x16x32_bf16(af[m], bf[n], acc[m][n], 0, 0, 0);
    __syncthreads();
  }

#pragma unroll
  for (int n = 0; n < 4; ++n) {
    const int col = col0 + wc * 64 + n * 16 + lr;
    const float bi = bias[col];
#pragma unroll
    for (int m = 0; m < 4; ++m) {
      const f32x4 v = acc[m][n];
      const int rbase = row0 + wr * 64 + m * 16 + lkh * 4;
#pragma unroll
      for (int j = 0; j < 4; ++j) {
        const int gr = rbase + j;
        if (gr < M) {
          float x = v[j] + bi;
          if (RELU) x = fmaxf(x, 0.f);
          C[(size_t)gr * Cstride + col] = f2b(x);
        }
      }
    }
  }
}

// ====== fused fp32-A projection GEMMs: 64-row tile, BK=64, wave = 16x128 strip ======
struct ProjG {
  const float* A[2];
  int Kin[2], Kp[2];
  const ushort* Wt[2];
  const float* bias[2];
  ushort* C[2];
  int M[2];
  int blkStart[3];
};

__global__ __launch_bounds__(256)
void gemm_proj(ProjG pg)
{
  __shared__ ushort As[64 * LS2];
  __shared__ ushort Bs[128 * LS2];
  const int bid = blockIdx.x;
  const int t = (bid >= pg.blkStart[1]) ? 1 : 0;
  const int row0 = (bid - pg.blkStart[t]) << 6;
  const float* A = pg.A[t];
  const ushort* Wt = pg.Wt[t];
  const int Kin = pg.Kin[t], Kp = pg.Kp[t], M = pg.M[t];
  const int tid = threadIdx.x;
  const int l = tid & 63, wid = tid >> 6;
  const int lr = l & 15, lkh = l >> 4;
  const int ar2 = tid >> 2, aq2 = tid & 3;   // A: 64 rows x 16 floats/thread
  const int br2 = tid >> 1, bh2 = tid & 1;   // B: 128 rows x 4 chunks

  f32x4 acc[8];
#pragma unroll
  for (int n = 0; n < 8; ++n) acc[n] = (f32x4)0.f;

  float4 pf[4];
  uint4 pb[4];
  auto loadP = [&](int kk) {
    const int gk = kk + aq2 * 16;
    const int gr = row0 + ar2;
#pragma unroll
    for (int q = 0; q < 4; ++q) pf[q] = make_float4(0.f, 0.f, 0.f, 0.f);
    if (gr < M) {
      const float* ap = A + (size_t)gr * Kin + gk;
      if (gk + 15 < Kin) {
#pragma unroll
        for (int q = 0; q < 4; ++q) pf[q] = *(const float4*)(ap + q * 4);
      } else {
        float tv[16];
#pragma unroll
        for (int j = 0; j < 16; ++j) tv[j] = (gk + j < Kin) ? ap[j] : 0.f;
#pragma unroll
        for (int q = 0; q < 4; ++q)
          pf[q] = make_float4(tv[q * 4], tv[q * 4 + 1], tv[q * 4 + 2], tv[q * 4 + 3]);
      }
    }
    const ushort* bp = Wt + (size_t)br2 * Kp + kk + bh2 * 32;
#pragma unroll
    for (int j = 0; j < 4; ++j) pb[j] = *(const uint4*)(bp + j * 8);
  };

  loadP(0);
  for (int kk = 0; kk < Kp; kk += 64) {
    {
      uint4 w0, w1;
      w0.x = f2b(pf[0].x) | ((uint)f2b(pf[0].y) << 16);
      w0.y = f2b(pf[0].z) | ((uint)f2b(pf[0].w) << 16);
      w0.z = f2b(pf[1].x) | ((uint)f2b(pf[1].y) << 16);
      w0.w = f2b(pf[1].z) | ((uint)f2b(pf[1].w) << 16);
      w1.x = f2b(pf[2].x) | ((uint)f2b(pf[2].y) << 16);
      w1.y = f2b(pf[2].z) | ((uint)f2b(pf[2].w) << 16);
      w1.z = f2b(pf[3].x) | ((uint)f2b(pf[3].y) << 16);
      w1.w = f2b(pf[3].z) | ((uint)f2b(pf[3].w) << 16);
      *(uint4*)&As[ar2 * LS2 + aq2 * 16] = w0;
      *(uint4*)&As[ar2 * LS2 + aq2 * 16 + 8] = w1;
#pragma unroll
      for (int j = 0; j < 4; ++j)
        *(uint4*)&Bs[br2 * LS2 + (bh2 * 4 + j) * 8] = pb[j];
    }
    __syncthreads();
    if (kk + 64 < Kp) loadP(kk + 64);
#pragma unroll
    for (int ks = 0; ks < 2; ++ks) {
      const bf16x8 af = *(const bf16x8*)&As[(wid * 16 + lr) * LS2 + ks * 32 + lkh * 8];
      bf16x8 bfv[8];
#pragma unroll
      for (int n = 0; n < 8; ++n)
        bfv[n] = *(const bf16x8*)&Bs[(n * 16 + lr) * LS2 + ks * 32 + lkh * 8];
#pragma unroll
      for (int n = 0; n < 8; ++n)
        acc[n] = __builtin_amdgcn_mfma_f32_16x16x32_bf16(af, bfv[n], acc[n], 0, 0, 0);
    }
    __syncthreads();
  }

  const float* bias = pg.bias[t];
  ushort* C = pg.C[t];
  const int rbase = row0 + wid * 16 + lkh * 4;
#pragma unroll
  for (int n = 0; n < 8; ++n) {
    const int col = n * 16 + lr;
    const float bi = bias[col];
    const f32x4 v = acc[n];
#pragma unroll
    for (int j = 0; j < 4; ++j) {
      const int gr = rbase + j;
      if (gr < M) C[(size_t)gr * 128 + col] = f2b(v[j] + bi);
    }
  }
}

// ================= weight conversion =================
__global__ void conv_wt(const float* __restrict__ W, ushort* __restrict__ Wt,
                        int K, int N, int Kp)
{
  const int kp = blockIdx.x * 256 + threadIdx.x;
  const int n = blockIdx.y;
  if (kp >= Kp) return;
  const float v = (kp < K) ? W[(size_t)kp * N + n] : 0.f;
  Wt[(size_t)n * Kp + kp] = f2b(v);
}

__global__ void conv_wcat(const float* __restrict__ Wl, const float* __restrict__ bl,
                          const float* __restrict__ Wr, const float* __restrict__ br,
                          ushort* __restrict__ WC, float* __restrict__ BC)
{
  const int KT[5]   = {512, 384, 256, 256, 256};
  const int TOFF[5] = {0, 512 * 128, 896 * 128, 1152 * 128, 1408 * 128};
  const int RL[5][3] = {{0, 4, 7}, {1, 2, -1}, {3, -1, -1}, {5, -1, -1}, {6, -1, -1}};
  const int NS[5] = {3, 2, 1, 1, 1};
  const int lt = blockIdx.y;
  const int lay = lt / 5, tt = lt % 5;
  const int idx = blockIdx.x * 256 + threadIdx.x;
  const int kk = idx >> 7, n = idx & 127;
  const int Kt = KT[tt];
  ushort* w = WC + (size_t)lay * (1664 * 128) + TOFF[tt] + (size_t)n * Kt;
  float s = 0.f;
  for (int q = 0; q < NS[tt]; ++q) {
    const int r = RL[tt][q];
    s += Wr[((size_t)lay * 8 + r) * 16384 + kk * 128 + n];
    w[(q + 1) * 128 + kk] = f2b(Wl[((size_t)lay * 8 + r) * 16384 + kk * 128 + n]);
  }
  w[kk] = f2b(s);
  if (kk == 0) {
    float b = 0.f;
    for (int q = 0; q < NS[tt]; ++q) {
      const int r = RL[tt][q];
      b += bl[(lay * 8 + r) * 128 + n] + br[(lay * 8 + r) * 128 + n];
    }
    BC[lt * 128 + n] = b;
  }
}

// head weight fold: WH[256][512]; seg0..2 = v_W1^T, seg3 = (xo_W @ v_W1[384:])^T
__global__ void conv_head(const float* __restrict__ vW1, const float* __restrict__ vb1,
                          const float* __restrict__ xoW, const float* __restrict__ xob,
                          ushort* __restrict__ WH, float* __restrict__ BH)
{
  const int idx = blockIdx.x * 256 + threadIdx.x;   // 256*512
  const int n = idx >> 9, k = idx & 511;
  if (k < 384) {
    WH[(size_t)n * 512 + k] = f2b(vW1[(size_t)k * 256 + n]);
  } else {
    const int c = k - 384;
    float s = 0.f;
    for (int d = 0; d < 128; ++d)
      s += xoW[c * 128 + d] * vW1[(size_t)(384 + d) * 256 + n];
    WH[(size_t)n * 512 + k] = f2b(s);
    if (c == 0) {
      float bb = vb1[n];
      for (int d = 0; d < 128; ++d)
        bb += xob[d] * vW1[(size_t)(384 + d) * 256 + n];
      BH[n] = bb;
    }
  }
}

__global__ void concat_bias2(const float* __restrict__ a, const float* __restrict__ b,
                             float* __restrict__ o)
{
  const int i = threadIdx.x;
  o[i] = (i < 128) ? a[i] : b[i - 128];
}

__global__ void conv_f2b_kernel(const float* __restrict__ in, ushort* __restrict__ out, int n)
{
  const int i = blockIdx.x * 256 + threadIdx.x;
  if (i < n) out[i] = f2b(in[i]);
}

// ================= small projection MLPs (bf16 out) =================
__global__ void proj_lt_kernel(const float* __restrict__ X, const float* __restrict__ W1,
                               const float* __restrict__ b1, const float* __restrict__ W2,
                               const float* __restrict__ b2, ushort* __restrict__ Y, int n)
{
  __shared__ float xs[4];
  __shared__ float hid[64];
  const int node = blockIdx.x, tid = threadIdx.x;
  if (node >= n) return;
  if (tid < 4) xs[tid] = X[(size_t)node * 4 + tid];
  __syncthreads();
  if (tid < 64) {
    float a = b1[tid];
#pragma unroll
    for (int k = 0; k < 4; ++k) a += xs[k] * W1[k * 64 + tid];
    hid[tid] = fmaxf(a, 0.f);
  }
  __syncthreads();
  float o = b2[tid];
  for (int k = 0; k < 64; ++k) o += hid[k] * W2[k * 128 + tid];
  Y[(size_t)node * 128 + tid] = f2b(o);
}

__global__ void proj_comm_kernel(const float* __restrict__ X, const float* __restrict__ W1,
                                 const float* __restrict__ b1, const float* __restrict__ W2,
                                 const float* __restrict__ b2, ushort* __restrict__ Y, int n)
{
  __shared__ float xs[65];
  __shared__ float hid[128];
  const int node = blockIdx.x, tid = threadIdx.x;
  if (node >= n) return;
  if (tid < 65) xs[tid] = X[(size_t)node * 65 + tid];
  __syncthreads();
  float a = b1[tid];
  for (int k = 0; k < 65; ++k) a += xs[k] * W1[k * 128 + tid];
  hid[tid] = fmaxf(a, 0.f);
  __syncthreads();
  float o = b2[tid];
  for (int k = 0; k < 128; ++k) o += hid[k] * W2[k * 128 + tid];
  Y[(size_t)node * 128 + tid] = f2b(o);
}

// ================= fused CSR build =================
struct EdgesAll {
  const int* src[8];
  const int* dst[8];
  int estart[9];
  int f9off[8];
};

__global__ void hist_all(EdgesAll ea, int* __restrict__ deg)
{
  const int e = blockIdx.x * 256 + threadIdx.x;
  if (e >= ea.estart[8]) return;
  int r = 0;
  while (e >= ea.estart[r + 1]) ++r;
  const int el = e - ea.estart[r];
  atomicAdd(&deg[ea.f9off[r] + ea.dst[r][el]], 1);
}

__global__ void fill_all(EdgesAll ea, const int* __restrict__ rp,
                         int* __restrict__ cur, int2* __restrict__ col)
{
  const int e = blockIdx.x * 256 + threadIdx.x;
  if (e >= ea.estart[8]) return;
  int r = 0;
  while (e >= ea.estart[r + 1]) ++r;
  const int el = e - ea.estart[r];
  const int d = ea.f9off[r] + ea.dst[r][el];
  const int p = atomicAdd(&cur[d], 1);
  col[rp[d] + p] = make_int2(ea.src[r][el], el);
}

__global__ __launch_bounds__(256)
void scan_blk(const int* __restrict__ in, int* __restrict__ out,
              int* __restrict__ bsum, int n)
{
  __shared__ int wsum[4];
  const int t = threadIdx.x;
  const int base = blockIdx.x * 1024 + t * 4;
  const int v0 = (base + 0 < n) ? in[base + 0] : 0;
  const int v1 = (base + 1 < n) ? in[base + 1] : 0;
  const int v2 = (base + 2 < n) ? in[base + 2] : 0;
  const int v3 = (base + 3 < n) ? in[base + 3] : 0;
  const int s = v0 + v1 + v2 + v3;
  const int lane = t & 63;
  int incl = s;
#pragma unroll
  for (int m = 1; m < 64; m <<= 1) {
    const int o = __shfl_up(incl, m);
    if (lane >= m) incl += o;
  }
  const int wid = t >> 6;
  if (lane == 63) wsum[wid] = incl;
  __syncthreads();
  int woff = 0;
#pragma unroll
  for (int w = 0; w < 3; ++w) woff += (w < wid) ? wsum[w] : 0;
  int run = woff + incl - s;
  if (base + 0 < n) out[base + 0] = run; run += v0;
  if (base + 1 < n) out[base + 1] = run; run += v1;
  if (base + 2 < n) out[base + 2] = run; run += v2;
  if (base + 3 < n) out[base + 3] = run;
  if (bsum != nullptr && t == 255) bsum[blockIdx.x] = woff + incl;
}

__global__ void scan_add(int* __restrict__ rp, const int* __restrict__ bsum, int n)
{
  const int i = blockIdx.x * 1024 + threadIdx.x * 4;
  const int add = bsum[blockIdx.x];
#pragma unroll
  for (int k = 0; k < 4; ++k)
    if (i + k < n) rp[i + k] += add;
}

// ======== F9: ONE THREAD per node (deg is tiny); r6 handled by f9_topic ========
struct F9All {
  const float* tt[8];
  int f9off[9];
};

__global__ __launch_bounds__(256)
void f9_thread(F9All fa, const int2* __restrict__ col, const int* __restrict__ rp,
               const float* __restrict__ w0p, const float* __restrict__ b0p,
               const float* __restrict__ wkp, const float* __restrict__ bkp,
               float* __restrict__ F9)
{
  const int node = blockIdx.x * 256 + threadIdx.x;
  if (node >= F9TOT) return;
  float* fo = F9 + (size_t)node * 9;
  if (node >= 312000 && node < 312115) {   // r6 range: zero (f9_topic accumulates)
#pragma unroll
    for (int k = 0; k < 9; ++k) fo[k] = 0.f;
    return;
  }
  int r = 0;
  while (node >= fa.f9off[r + 1]) ++r;
  const float* tvals = fa.tt[r];
  const int e0 = rp[node], e1 = rp[node + 1];
  const float w0 = w0p[0], b0 = b0p[0];
  float wk[8], bk[8];
#pragma unroll
  for (int k = 0; k < 8; ++k) { wk[k] = wkp[k]; bk[k] = bkp[k]; }
  float st = 0.f;
  float fk[8];
#pragma unroll
  for (int k = 0; k < 8; ++k) fk[k] = 0.f;
  for (int e = e0; e < e1; ++e) {
    const float tv = tvals[col[e].y];
    st += tv;
#pragma unroll
    for (int k = 0; k < 8; ++k) fk[k] += __sinf(tv * wk[k] + bk[k]);
  }
  fo[0] = st * w0 + (float)(e1 - e0) * b0;
#pragma unroll
  for (int k = 0; k < 8; ++k) fo[1 + k] = fk[k];
}

// r6 (topic, deg~435): 64 threads per node, local sums then 9 atomics each
__global__ void f9_topic(const int2* __restrict__ col, const int* __restrict__ rp,
                         const float* __restrict__ tvals,
                         const float* __restrict__ w0p, const float* __restrict__ b0p,
                         const float* __restrict__ wkp, const float* __restrict__ bkp,
                         float* __restrict__ F9)
{
  const int t = blockIdx.x * 256 + threadIdx.x;
  if (t >= cNT * 64) return;
  const int node = t >> 6, j = t & 63;
  const int e0 = rp[node], e1 = rp[node + 1];
  const float w0 = w0p[0], b0 = b0p[0];
  float wk[8], bk[8];
#pragma unroll
  for (int k = 0; k < 8; ++k) { wk[k] = wkp[k]; bk[k] = bkp[k]; }
  float st = 0.f;
  float fk[8];
#pragma unroll
  for (int k = 0; k < 8; ++k) fk[k] = 0.f;
  int cnt = 0;
  for (int e = e0 + j; e < e1; e += 64) {
    const float tv = tvals[col[e].y];
    st += tv; ++cnt;
#pragma unroll
    for (int k = 0; k < 8; ++k) fk[k] += __sinf(tv * wk[k] + bk[k]);
  }
  float* fo = F9 + (size_t)node * 9;
  atomicAdd(fo, st * w0 + (float)cnt * b0);
#pragma unroll
  for (int k = 0; k < 8; ++k) atomicAdd(fo + 1 + k, fk[k]);
}

// ======== fused per-layer gather: QUARTER-WAVE per node, uint4 rows ========
constexpr int QW_SPLIT0 = 312000;             // nodes before rel6 split section
constexpr int QW_SPLIT1 = 312000 + 115 * 64;  // end of split section
constexpr int QW_TOTAL  = QW_SPLIT1 + 50000;  // + rel7 nodes

struct GatherAll {
  const ushort* Hsrc[8];
  const float* eW;      // edge_W base
  const float* eb;      // edge_b base
  const int2* col;
  const int* rp;
  const float* F9;
  ushort* S;
  float* SPtop;
  int f9off[7];   // {0,50000,150000,250000,260000,310000,312000}
};

__global__ __launch_bounds__(256)
void gather_all(GatherAll ga)
{
  const int qw = (blockIdx.x * 256 + threadIdx.x) >> 4;
  if (qw >= QW_TOTAL) return;
  const int lq = threadIdx.x & 15;
  int node, r, splitj = -1;
  if (qw < QW_SPLIT0) {
    node = qw;
    r = 0;
    while (node >= ga.f9off[r + 1]) ++r;     // r in 0..5
  } else if (qw < QW_SPLIT1) {
    const int lw = qw - QW_SPLIT0;
    node = QW_SPLIT0 + (lw >> 6);
    splitj = lw & 63;
    r = 6;
  } else {
    node = 312115 + (qw - QW_SPLIT1);
    r = 7;
  }
  const int e0 = ga.rp[node], e1 = ga.rp[node + 1];
  const uint4* H4 = (const uint4*)ga.Hsrc[r];
  float a[8];
#pragma unroll
  for (int i = 0; i < 8; ++i) a[i] = 0.f;

#define ACC8(v)                                              \
  { a[0] += b2f((ushort)(v).x); a[1] += b2f((ushort)((v).x >> 16)); \
    a[2] += b2f((ushort)(v).y); a[3] += b2f((ushort)((v).y >> 16)); \
    a[4] += b2f((ushort)(v).z); a[5] += b2f((ushort)((v).z >> 16)); \
    a[6] += b2f((ushort)(v).w); a[7] += b2f((ushort)((v).w >> 16)); }

  if (splitj >= 0) {
    int e = e0 + splitj;
    for (; e + 64 < e1; e += 128) {
      const int s0 = ga.col[e].x, s1 = ga.col[e + 64].x;
      const uint4 v0 = H4[(size_t)s0 * 16 + lq];
      const uint4 v1 = H4[(size_t)s1 * 16 + lq];
      ACC8(v0); ACC8(v1);
    }
    if (e < e1) { const uint4 v = H4[(size_t)ga.col[e].x * 16 + lq]; ACC8(v); }
    float* p = &ga.SPtop[(size_t)(node - QW_SPLIT0) * 128 + lq * 8];
#pragma unroll
    for (int i = 0; i < 8; ++i) atomicAdd(p + i, a[i]);
    return;
  }
  int e = e0;
  for (; e + 3 < e1; e += 4) {
    const int s0 = ga.col[e].x, s1 = ga.col[e + 1].x;
    const int s2 = ga.col[e + 2].x, s3 = ga.col[e + 3].x;
    const uint4 v0 = H4[(size_t)s0 * 16 + lq];
    const uint4 v1 = H4[(size_t)s1 * 16 + lq];
    const uint4 v2 = H4[(size_t)s2 * 16 + lq];
    const uint4 v3 = H4[(size_t)s3 * 16 + lq];
    ACC8(v0); ACC8(v1); ACC8(v2); ACC8(v3);
  }
  if (e + 1 < e1) {
    const int s0 = ga.col[e].x, s1 = ga.col[e + 1].x;
    const uint4 v0 = H4[(size_t)s0 * 16 + lq];
    const uint4 v1 = H4[(size_t)s1 * 16 + lq];
    ACC8(v0); ACC8(v1);
    e += 2;
  }
  if (e < e1) { const uint4 v = H4[(size_t)ga.col[e].x * 16 + lq]; ACC8(v); }

  const float* eW = ga.eW + (size_t)r * 9 * 128;
  const float* eb = ga.eb + (size_t)r * 128;
  float f9[9];
#pragma unroll
  for (int k = 0; k < 9; ++k) f9[k] = ga.F9[(size_t)node * 9 + k];
  const int degn = e1 - e0;
  const int j0 = lq * 8;
#pragma unroll
  for (int k = 0; k < 9; ++k) {
#pragma unroll
    for (int i = 0; i < 8; ++i) a[i] += f9[k] * eW[k * 128 + j0 + i];
  }
  const float rinv = 1.f / fmaxf((float)degn, 1.f);
#pragma unroll
  for (int i = 0; i < 8; ++i) a[i] *= rinv;
  if (degn > 0) {
#pragma unroll
    for (int i = 0; i < 8; ++i) a[i] += eb[j0 + i];
  }
  uint4 o;
  o.x = (uint)f2b(a[0]) | ((uint)f2b(a[1]) << 16);
  o.y = (uint)f2b(a[2]) | ((uint)f2b(a[3]) << 16);
  o.z = (uint)f2b(a[4]) | ((uint)f2b(a[5]) << 16);
  o.w = (uint)f2b(a[6]) | ((uint)f2b(a[7]) << 16);
  ((uint4*)ga.S)[(size_t)node * 16 + lq] = o;
#undef ACC8
}

__global__ void finalize_split(const float* __restrict__ SP, const int* __restrict__ rp,
                               const float* __restrict__ F9, const float* __restrict__ eW,
                               const float* __restrict__ eb, ushort* __restrict__ S, int nd)
{
  const int gw = (blockIdx.x * blockDim.x + threadIdx.x) >> 6;
  if (gw >= nd) return;
  const int lane = threadIdx.x & 63;
  const int degn = rp[gw + 1] - rp[gw];
  const int j = lane * 2;
  const float2 sv = *(const float2*)&SP[(size_t)gw * 128 + j];
  float f9[9];
#pragma unroll
  for (int k = 0; k < 9; ++k) f9[k] = F9[(size_t)gw * 9 + k];
  float o0 = sv.x, o1 = sv.y;
#pragma unroll
  for (int k = 0; k < 9; ++k) {
    o0 += f9[k] * eW[k * 128 + j];
    o1 += f9[k] * eW[k * 128 + j + 1];
  }
  const float rinv = 1.f / fmaxf((float)degn, 1.f);
  o0 *= rinv; o1 *= rinv;
  if (degn > 0) { o0 += eb[j]; o1 += eb[j + 1]; }
  ((uint*)S)[(size_t)gw * 64 + lane] = (uint)f2b(o0) | ((uint)f2b(o1) << 16);
}

// ======== h_bill: quarter-wave per node, uint4 rows ========
__global__ __launch_bounds__(256)
void gather_bill(const ushort* __restrict__ H1, const int2* __restrict__ col,
                 const int* __restrict__ rp, const ushort* __restrict__ H0,
                 ushort* __restrict__ S, int nB)
{
  const int qw = (blockIdx.x * 256 + threadIdx.x) >> 4;
  if (qw >= nB) return;
  const int lq = threadIdx.x & 15;
  const int e0 = rp[qw], e1 = rp[qw + 1];
  const uint4* H14 = (const uint4*)H1;
  float a[8];
#pragma unroll
  for (int i = 0; i < 8; ++i) a[i] = 0.f;
#define ACC8(v)                                              \
  { a[0] += b2f((ushort)(v).x); a[1] += b2f((ushort)((v).x >> 16)); \
    a[2] += b2f((ushort)(v).y); a[3] += b2f((ushort)((v).y >> 16)); \
    a[4] += b2f((ushort)(v).z); a[5] += b2f((ushort)((v).z >> 16)); \
    a[6] += b2f((ushort)(v).w); a[7] += b2f((ushort)((v).w >> 16)); }
  int e = e0;
  for (; e + 1 < e1; e += 2) {
    const int s0 = col[e].x, s1 = col[e + 1].x;
    const uint4 v0 = H14[(size_t)s0 * 16 + lq];
    const uint4 v1 = H14[(size_t)s1 * 16 + lq];
    ACC8(v0); ACC8(v1);
  }
  if (e < e1) { const uint4 v = H14[(size_t)col[e].x * 16 + lq]; ACC8(v); }
#undef ACC8
  const float rc = 1.f / ((float)(e1 - e0) + 1e-6f);
  const uint4 h0 = ((const uint4*)H0)[(size_t)qw * 16 + lq];
  uint4 o;
  o.x = (uint)f2b(0.5f * b2f((ushort)h0.x) + 0.5f * a[0] * rc)
      | ((uint)f2b(0.5f * b2f((ushort)(h0.x >> 16)) + 0.5f * a[1] * rc) << 16);
  o.y = (uint)f2b(0.5f * b2f((ushort)h0.y) + 0.5f * a[2] * rc)
      | ((uint)f2b(0.5f * b2f((ushort)(h0.y >> 16)) + 0.5f * a[3] * rc) << 16);
  o.z = (uint)f2b(0.5f * b2f((ushort)h0.z) + 0.5f * a[4] * rc)
      | ((uint)f2b(0.5f * b2f((ushort)(h0.z >> 16)) + 0.5f * a[5] * rc) << 16);
  o.w = (uint)f2b(0.5f * b2f((ushort)h0.w) + 0.5f * a[6] * rc)
      | ((uint)f2b(0.5f * b2f((ushort)(h0.w >> 16)) + 0.5f * a[7] * rc) << 16);
  ((uint4*)S)[(size_t)qw * 16 + lq] = o;
}

// ================= per-vote softmax attention (1 wave/vote) =================
__global__ __launch_bounds__(256)
void attn_lite(const ushort* __restrict__ Ql, const ushort* __restrict__ KVb,
               const int* __restrict__ vote_lt, const int* __restrict__ vote_bv,
               const int* __restrict__ isv_dst, const int* __restrict__ t_for_bill,
               ushort* __restrict__ CT, int* __restrict__ tpv, int nV)
{
  const int gw = (blockIdx.x * blockDim.x + threadIdx.x) >> 6;
  if (gw >= nV) return;
  const int lane = threadIdx.x & 63;
  const int bv = vote_bv[gw];
  const int lt = vote_lt[gw];
  const int b = isv_dst[bv];
  if (lane == 0) tpv[gw] = t_for_bill[b];
  const uint q  = ((const uint*)Ql)[(size_t)lt * 64 + lane];
  const uint kk = ((const uint*)KVb)[(size_t)b * 128 + lane];
  const uint vv = ((const uint*)KVb)[(size_t)b * 128 + 64 + lane];
  const float q0 = b2f((ushort)q),  q1 = b2f((ushort)(q >> 16));
  const float k0 = b2f((ushort)kk), k1 = b2f((ushort)(kk >> 16));
  float s = q0 * k0 + q1 * k1;
#pragma unroll
  for (int m = 1; m < 16; m <<= 1) s += __shfl_xor(s, m);   // 16-lane head groups
  s *= 0.17677669529663687f;                                // 1/sqrt(32)
  float mx = fmaxf(s, __shfl_xor(s, 16));
  mx = fmaxf(mx, __shfl_xor(mx, 32));
  const float e = __expf(s - mx);
  float den = e + __shfl_xor(e, 16);
  den += __shfl_xor(den, 32);
  const float a = e / den;
  const float v0f = b2f((ushort)vv), v1f = b2f((ushort)(vv >> 16));
  ((uint*)CT)[(size_t)gw * 64 + lane] =
      (uint)f2b(a * v0f) | ((uint)f2b(a * v1f) << 16);
}

// ================= final 128 -> 3 (bf16 G) =================
__global__ void final_out(const ushort* __restrict__ G, const float* __restrict__ Wo,
                          const float* __restrict__ bo, float* __restrict__ out,
                          int v0, int nV)
{
  const int wave = (blockIdx.x * blockDim.x + threadIdx.x) >> 6;
  const int lane = threadIdx.x & 63;
  if (wave >= nV) return;
  const ushort* g = G + (size_t)wave * 128;
  const float x0 = b2f(g[lane]), x1 = b2f(g[64 + lane]);
  float s0 = x0 * Wo[lane * 3 + 0] + x1 * Wo[(64 + lane) * 3 + 0];
  float s1 = x0 * Wo[lane * 3 + 1] + x1 * Wo[(64 + lane) * 3 + 1];
  float s2 = x0 * Wo[lane * 3 + 2] + x1 * Wo[(64 + lane) * 3 + 2];
#pragma unroll
  for (int m = 1; m < 64; m <<= 1) {
    s0 += __shfl_xor(s0, m);
    s1 += __shfl_xor(s1, m);
    s2 += __shfl_xor(s2, m);
  }
  if (lane == 0) {
    float* o = out + (size_t)(v0 + wave) * 3;
    o[0] = s0 + bo[0]; o[1] = s1 + bo[1]; o[2] = s2 + bo[2];
  }
}

// ================= host side =================
static inline int cdiv(int a, int b) { return (a + b - 1) / b; }

extern "C" void kernel_launch(void* const* d_in, const int* in_sizes, int n_in,
                              void* d_out, int out_size, void* d_ws, size_t ws_size,
                              hipStream_t stream)
{
  (void)in_sizes; (void)n_in; (void)out_size;

  const float* x_bill = (const float*)d_in[0];
  const float* x_bv   = (const float*)d_in[1];
  const float* x_lt   = (const float*)d_in[2];
  const float* x_comm = (const float*)d_in[3];
  const float* pb_W  = (const float*)d_in[4];
  const float* pb_b  = (const float*)d_in[5];
  const float* pbv_W = (const float*)d_in[6];
  const float* pbv_b = (const float*)d_in[7];
  const float* plt_W1 = (const float*)d_in[8];
  const float* plt_b1 = (const float*)d_in[9];
  const float* plt_W2 = (const float*)d_in[10];
  const float* plt_b2 = (const float*)d_in[11];
  const float* pc_W1 = (const float*)d_in[12];
  const float* pc_b1 = (const float*)d_in[13];
  const float* pc_W2 = (const float*)d_in[14];
  const float* pc_b2 = (const float*)d_in[15];
  const float* topic_emb = (const float*)d_in[16];
  const float* t2v_w0 = (const float*)d_in[17];
  const float* t2v_b0 = (const float*)d_in[18];
  const float* t2v_wk = (const float*)d_in[19];
  const float* t2v_bk = (const float*)d_in[20];
  const float* edge_W = (const float*)d_in[21];
  const float* edge_b = (const float*)d_in[22];
  const float* sage_Wl = (const float*)d_in[23];
  const float* sage_bl = (const float*)d_in[24];
  const float* sage_Wr = (const float*)d_in[25];
  const float* sage_br = (const float*)d_in[26];
  const float* ln_g = (const float*)d_in[27];
  const float* ln_b = (const float*)d_in[28];
  const float* xq_W = (const float*)d_in[29];
  const float* xq_b = (const float*)d_in[30];
  const float* xk_W = (const float*)d_in[31];
  const float* xk_b = (const float*)d_in[32];
  const float* xv_W = (const float*)d_in[33];
  const float* xv_b = (const float*)d_in[34];
  const float* xo_W = (const float*)d_in[35];
  const float* xo_b = (const float*)d_in[36];
  const float* v_W1 = (const float*)d_in[37];
  const float* v_b1 = (const float*)d_in[38];
  const float* v_W2 = (const float*)d_in[39];
  const float* v_b2 = (const float*)d_in[40];
  const float* v_Wo = (const float*)d_in[41];
  const float* v_bo = (const float*)d_in[42];
  const float* t_isv   = (const float*)d_in[43];
  const float* t_vote  = (const float*)d_in[44];
  const float* t_rev   = (const float*)d_in[45];
  const float* t_about = (const float*)d_in[46];
  const int* ei_isv   = (const int*)d_in[47];
  const int* ei_vote  = (const int*)d_in[48];
  const int* ei_rev   = (const int*)d_in[49];
  const int* ei_about = (const int*)d_in[50];
  const int* t_for_bill = (const int*)d_in[51];
  const int* vote_lt = (const int*)d_in[52];
  const int* vote_bv = (const int*)d_in[53];
  float* out = (float*)d_out;

  const int OFFS[5] = {0, cNB, cNB + cNBV, cNB + cNBV + cNLT, cNB + cNBV + cNLT + cNC};
  const int NSZ[5]  = {cNB, cNBV, cNLT, cNC, cNT};

  // -------- workspace layout (bytes) --------
  char* w = (char*)d_ws;
  const size_t szHb = (size_t)cNTOT * 128 * 2;            // 41.5 MB
  const size_t szS  = (size_t)F9TOT * 128 * 2;            // 92.7 MB
  ushort* Hb   = (ushort*)w;
  ushort* NEWb = (ushort*)(w + szHb);                     // SPtop / Uc / Gc scratch
  ushort* Sall = (ushort*)(w + 2 * szHb);
  size_t off = 2 * szHb + szS;
  ushort* WT_pb  = (ushort*)(w + off); off += (size_t)128 * 832 * 2;
  ushort* WT_pbv = (ushort*)(w + off); off += (size_t)128 * 448 * 2;
  ushort* WC     = (ushort*)(w + off); off += (size_t)3 * 1664 * 128 * 2;
  ushort* WT_v2  = (ushort*)(w + off); off += (size_t)128 * 256 * 2;
  ushort* WT_q   = (ushort*)(w + off); off += (size_t)128 * 128 * 2;
  ushort* WT_kv  = (ushort*)(w + off); off += (size_t)256 * 128 * 2;
  ushort* WH     = (ushort*)(w + off); off += (size_t)256 * 512 * 2;
  off = (off + 15) & ~(size_t)15;
  float* BC  = (float*)(w + off); off += (size_t)15 * 128 * 4;
  float* BH  = (float*)(w + off); off += (size_t)256 * 4;
  float* BKV = (float*)(w + off); off += (size_t)256 * 4;
  int* rp = (int*)(w + off); off += (size_t)(F9TOT + 1) * 4;
  off = (off + 7) & ~(size_t)7;
  int2* col = (int2*)(w + off); off += (size_t)ETOT * 8;
  float* F9 = (float*)(w + off); off += (size_t)F9TOT * 9 * 4;   // 13.0 MB
  int* tpv = (int*)(w + off); off += (size_t)cNVOTE * 4;
  if (ws_size < off) return;

  // transients aliased into Sall (dead before first gather use)
  int* deg  = (int*)Sall;
  int* cur  = deg + (F9TOT + 1);
  int* bsum = cur + F9TOT;
  // topic split partial buffer aliased into NEWb
  float* SPtop = (float*)NEWb;                                    // 115*128 fp32
  // post-layer aliases: Sall holds hbill_b | CT | KVb | Ql  (66.6 MB <= 92.7)
  ushort* hbill_b = Sall;                                         // 50000*128
  ushort* CT  = Sall + (size_t)cNB * 128;                         // 100000*128
  ushort* KVb = CT + (size_t)cNVOTE * 128;                        // 50000*256
  ushort* Ql  = KVb + (size_t)cNB * 256;                          // 10000*128
  // NEWb post-LN aliases: Uc | Gc (38.4 MB <= 41.5)
  ushort* Uc = NEWb;                                              // 50000*256
  ushort* Gc = NEWb + (size_t)50000 * 256;                        // 50000*128

  // relation tables
  const int F9OFF[9] = {0, 50000, 150000, 250000, 260000, 310000, 312000, 312115, 362115};
  const int ESTART[9] = {0, 100000, 200000, 600000, 1000000, 1050000, 1100000, 1150000, 1200000};
  const int SRCT[8] = {1, 0, 2, 1, 3, 0, 0, 4};
  const int* rel_src[8] = {ei_isv, ei_isv + cNBV, ei_vote, ei_vote + cEV,
                           ei_rev, ei_rev + cER, ei_about, ei_about + cNB};
  const int* rel_dst[8] = {ei_isv + cNBV, ei_isv, ei_vote + cEV, ei_vote,
                           ei_rev + cER, ei_rev, ei_about + cNB, ei_about};
  const float* rel_tt[8] = {t_isv, t_isv, t_vote, t_vote, t_rev, t_rev, t_about, t_about};

  // ---- 0. weight conversions ----
  conv_wt<<<dim3(4, 128), 256, 0, stream>>>(pb_W, WT_pb, 770, 128, 832);
  conv_wt<<<dim3(2, 128), 256, 0, stream>>>(pbv_W, WT_pbv, 390, 128, 448);
  conv_wt<<<dim3(1, 128), 256, 0, stream>>>(v_W2, WT_v2, 256, 128, 256);
  conv_wt<<<dim3(1, 128), 256, 0, stream>>>(xq_W, WT_q, 128, 128, 128);
  conv_wt<<<dim3(1, 128), 256, 0, stream>>>(xk_W, WT_kv, 128, 128, 128);
  conv_wt<<<dim3(1, 128), 256, 0, stream>>>(xv_W, WT_kv + 128 * 128, 128, 128, 128);
  conv_head<<<512, 256, 0, stream>>>(v_W1, v_b1, xo_W, xo_b, WH, BH);
  concat_bias2<<<1, 256, 0, stream>>>(xk_b, xv_b, BKV);
  conv_wcat<<<dim3(64, 15), 256, 0, stream>>>(sage_Wl, sage_bl, sage_Wr, sage_br, WC, BC);
  conv_f2b_kernel<<<cdiv(cNT * 128, 256), 256, 0, stream>>>(
      topic_emb, Hb + (size_t)OFFS[4] * 128, cNT * 128);

  // ---- 1. CSR build (fused) ----
  EdgesAll ea;
  for (int r = 0; r < 8; ++r) {
    ea.src[r] = rel_src[r]; ea.dst[r] = rel_dst[r]; ea.f9off[r] = F9OFF[r];
  }
  for (int r = 0; r < 9; ++r) ea.estart[r] = ESTART[r];
  const int nScan = F9TOT + 1;
  const int nb = cdiv(nScan, 1024);
  hipMemsetAsync(deg, 0, (size_t)nScan * sizeof(int), stream);
  hist_all<<<cdiv(ETOT, 256), 256, 0, stream>>>(ea, deg);
  scan_blk<<<nb, 256, 0, stream>>>(deg, rp, bsum, nScan);
  scan_blk<<<1, 256, 0, stream>>>(bsum, bsum, nullptr, nb);
  scan_add<<<nb, 256, 0, stream>>>(rp, bsum, nScan);
  hipMemsetAsync(cur, 0, (size_t)F9TOT * sizeof(int), stream);
  fill_all<<<cdiv(ETOT, 256), 256, 0, stream>>>(ea, rp, cur, col);

  // ---- 1b. F9 precompute (thread-per-node + topic split) ----
  F9All fa;
  for (int r = 0; r < 8; ++r) fa.tt[r] = rel_tt[r];
  for (int r = 0; r < 9; ++r) fa.f9off[r] = F9OFF[r];
  f9_thread<<<cdiv(F9TOT, 256), 256, 0, stream>>>(
      fa, col, rp, t2v_w0, t2v_b0, t2v_wk, t2v_bk, F9);
  f9_topic<<<cdiv(cNT * 64, 256), 256, 0, stream>>>(
      col, rp + F9OFF[6], t_about, t2v_w0, t2v_b0, t2v_wk, t2v_bk,
      F9 + (size_t)F9OFF[6] * 9);

  // ---- 2. initial projections (64-row tiles, BK=64) ----
  ProjG pg;
  pg.A[0] = x_bill; pg.Kin[0] = 770; pg.Kp[0] = 832; pg.Wt[0] = WT_pb;
  pg.bias[0] = pb_b; pg.C[0] = Hb + (size_t)OFFS[0] * 128; pg.M[0] = cNB;
  pg.A[1] = x_bv; pg.Kin[1] = 390; pg.Kp[1] = 448; pg.Wt[1] = WT_pbv;
  pg.bias[1] = pbv_b; pg.C[1] = Hb + (size_t)OFFS[1] * 128; pg.M[1] = cNBV;
  pg.blkStart[0] = 0; pg.blkStart[1] = cdiv(cNB, 64);
  pg.blkStart[2] = pg.blkStart[1] + cdiv(cNBV, 64);
  gemm_proj<<<pg.blkStart[2], 256, 0, stream>>>(pg);
  proj_lt_kernel<<<cNLT, 128, 0, stream>>>(x_lt, plt_W1, plt_b1, plt_W2, plt_b2,
                                           Hb + (size_t)OFFS[2] * 128, cNLT);
  proj_comm_kernel<<<cNC, 128, 0, stream>>>(x_comm, pc_W1, pc_b1, pc_W2, pc_b2,
                                            Hb + (size_t)OFFS[3] * 128, cNC);

  // ---- 3. SAGE layers (GEMM + fused LN writes H in place) ----
  GatherAll ga;
  for (int r = 0; r < 8; ++r) ga.Hsrc[r] = Hb + (size_t)OFFS[SRCT[r]] * 128;
  ga.eW = edge_W; ga.eb = edge_b; ga.col = col; ga.rp = rp; ga.F9 = F9;
  ga.S = Sall; ga.SPtop = SPtop;
  for (int r = 0; r < 7; ++r) ga.f9off[r] = F9OFF[r];

  SageG sg;
  const int KTt[5]   = {512, 384, 256, 256, 256};
  const int TOFFt[5] = {0, 512 * 128, 896 * 128, 1152 * 128, 1408 * 128};
  const int SEGOFF[5][3] = {{0, 260000, 312115}, {50000, 150000, -1},
                            {250000, -1, -1}, {310000, -1, -1}, {312000, -1, -1}};
  sg.blkStart[0] = 0;
  for (int t = 0; t < 5; ++t) {
    sg.M[t] = NSZ[t]; sg.Ktot[t] = KTt[t];
    sg.C[t] = Hb + (size_t)OFFS[t] * 128;                 // in-place (LN fused)
    sg.A[t][0] = Hb + (size_t)OFFS[t] * 128;
    for (int q = 0; q < 3; ++q)
      sg.A[t][q + 1] = (SEGOFF[t][q] >= 0) ? Sall + (size_t)SEGOFF[t][q] * 128 : nullptr;
    sg.blkStart[t + 1] = sg.blkStart[t] + cdiv(NSZ[t], 64);
  }

  for (int l = 0; l < cLAYERS; ++l) {
    hipMemsetAsync(SPtop, 0, (size_t)cNT * 128 * sizeof(float), stream);
    gather_all<<<cdiv(QW_TOTAL * 16, 256), 256, 0, stream>>>(ga);
    finalize_split<<<cdiv(cNT * 64, 256), 256, 0, stream>>>(
        SPtop, rp + F9OFF[6], F9 + (size_t)F9OFF[6] * 9,
        edge_W + (size_t)6 * 9 * 128, edge_b + (size_t)6 * 128,
        Sall + (size_t)F9OFF[6] * 128, cNT);
    for (int t = 0; t < 5; ++t) {
      sg.Wt[t] = WC + (size_t)l * (1664 * 128) + TOFFt[t];
      sg.bias[t] = BC + (size_t)(l * 5 + t) * 128;
      sg.lng[t] = ln_g + (size_t)(l * 5 + t) * 128;
      sg.lnb[t] = ln_b + (size_t)(l * 5 + t) * 128;
    }
    gemm_sage<<<sg.blkStart[5], 256, 0, stream>>>(sg);
  }

  // ---- 4. head ----
  gather_bill<<<cdiv(cNB * 16, 256), 256, 0, stream>>>(
      Hb + (size_t)OFFS[1] * 128, col, rp, Hb + (size_t)OFFS[0] * 128, hbill_b, cNB);
  gemm_abf<1, false><<<dim3(2, cdiv(cNB, 128)), 256, 0, stream>>>(
      hbill_b, hbill_b, hbill_b, hbill_b, 128, WT_kv, 128, BKV, KVb, 256, cNB);
  gemm_abf<1, false><<<dim3(1, cdiv(cNLT, 128)), 256, 0, stream>>>(
      Hb + (size_t)OFFS[2] * 128, nullptr, nullptr, nullptr, 128, WT_q, 128,
      xq_b, Ql, 128, cNLT);
  attn_lite<<<cdiv(cNVOTE * 64, 256), 256, 0, stream>>>(
      Ql, KVb, vote_lt, vote_bv, ei_isv + cNBV, t_for_bill, CT, tpv, cNVOTE);

  const int VCH = 50000;
  for (int v0 = 0; v0 < cNVOTE; v0 += VCH) {
    const int nv = (cNVOTE - v0 < VCH) ? (cNVOTE - v0) : VCH;
    gemm_gat4<true><<<dim3(2, cdiv(nv, 128)), 256, 0, stream>>>(
        Hb + (size_t)OFFS[2] * 128, vote_lt + v0,
        Hb + (size_t)OFFS[1] * 128, vote_bv + v0,
        Hb + (size_t)OFFS[4] * 128, tpv + v0,
        CT + (size_t)v0 * 128,
        WH, BH, Uc, 256, nv);
    gemm_abf<2, false><<<dim3(1, cdiv(nv, 128)), 256, 0, stream>>>(
        Uc, Uc + 128, nullptr, nullptr, 256, WT_v2, 256, v_b2, Gc, 128, nv);
    final_out<<<cdiv(nv, 4), 256, 0, stream>>>(Gc, v_Wo, v_bo, out, v0, nv);
  }
}

// Round 17
// 1261.012 us; speedup vs baseline: 1.1565x; 1.1565x over previous
//
#include <hip/hip_runtime.h>
#include <math.h>

// ---------------- problem constants ----------------
constexpr int cNB = 50000, cNBV = 100000, cNLT = 10000, cNC = 2000, cNT = 115;
constexpr int cEV = 400000, cER = 50000, cNVOTE = 100000;
constexpr int cNTOT = cNB + cNBV + cNLT + cNC + cNT;   // 162115
constexpr int cLAYERS = 3;
constexpr int F9TOT = 362115;   // sum of n_dst over 8 relations
constexpr int ETOT  = 1200000;  // sum of E over 8 relations
constexpr int LS = 40;          // LDS row stride in shorts (80B = 5*16B)

typedef __attribute__((ext_vector_type(8))) short bf16x8;
typedef __attribute__((ext_vector_type(4))) float f32x4;
union pack8 { uint4 u; bf16x8 v; };

__device__ __forceinline__ ushort f2b(float f) {
  union { float f; uint u; } v; v.f = f;
  uint r = v.u + 0x7fffu + ((v.u >> 16) & 1u);   // RNE
  return (ushort)(r >> 16);
}
__device__ __forceinline__ float b2f(ushort b) {
  union { uint u; float f; } v; v.u = ((uint)b) << 16; return v.f;
}

// ====== fused SAGE GEMM + LayerNorm epilogue: 64-row tile, wave = 16x128 strip ======
// Reads H_cur (A0) + Sall segments, writes LN(new) to H_next (ping-pong, NOT in place).
struct SageG {
  const ushort* A[5][4];
  const ushort* Wt[5];
  const float* bias[5];
  const float* lng[5];
  const float* lnb[5];
  ushort* C[5];
  int M[5];
  int Ktot[5];
  int blkStart[6];
};

__global__ __launch_bounds__(256)
void gemm_sage(SageG sg)
{
  __shared__ ushort As[64 * LS];
  __shared__ ushort Bs[128 * LS];
  const int bid = blockIdx.x;
  int t = 0;
  while (bid >= sg.blkStart[t + 1]) ++t;
  const int row0 = (bid - sg.blkStart[t]) << 6;
  const int M = sg.M[t], Ktot = sg.Ktot[t];
  const ushort* Wt = sg.Wt[t];
  const int tid = threadIdx.x;
  const int l = tid & 63, wid = tid >> 6;
  const int lr = l & 15, lkh = l >> 4;
  const int arow = tid >> 2, aq = tid & 3;   // staging: 64 rows x 4 quarters

  f32x4 acc[8];
#pragma unroll
  for (int n = 0; n < 8; ++n) acc[n] = (f32x4)0.f;

  uint4 pa, pb0, pb1;
  auto loadAB = [&](int kk) {
    const ushort* Ap = sg.A[t][kk >> 7];
    const int k0 = kk & 127;
    const int gr = row0 + arow;
    pa = make_uint4(0, 0, 0, 0);
    if (gr < M) pa = *(const uint4*)(Ap + (size_t)gr * 128 + k0 + aq * 8);
    pb0 = *(const uint4*)(Wt + (size_t)arow * Ktot + kk + aq * 8);
    pb1 = *(const uint4*)(Wt + (size_t)(arow + 64) * Ktot + kk + aq * 8);
  };

  loadAB(0);
  for (int kk = 0; kk < Ktot; kk += 32) {
    *(uint4*)&As[arow * LS + aq * 8] = pa;
    *(uint4*)&Bs[arow * LS + aq * 8] = pb0;
    *(uint4*)&Bs[(arow + 64) * LS + aq * 8] = pb1;
    __syncthreads();
    if (kk + 32 < Ktot) loadAB(kk + 32);
    const bf16x8 af = *(const bf16x8*)&As[(wid * 16 + lr) * LS + lkh * 8];
    bf16x8 bf[8];
#pragma unroll
    for (int n = 0; n < 8; ++n)
      bf[n] = *(const bf16x8*)&Bs[(n * 16 + lr) * LS + lkh * 8];
#pragma unroll
    for (int n = 0; n < 8; ++n)
      acc[n] = __builtin_amdgcn_mfma_f32_16x16x32_bf16(af, bf[n], acc[n], 0, 0, 0);
    __syncthreads();
  }

  const float* bias = sg.bias[t];
  const float* g = sg.lng[t];
  const float* bb = sg.lnb[t];
  ushort* C = sg.C[t];
  const int rbase = row0 + wid * 16 + lkh * 4;
  float bi[8], gv[8], bv[8];
#pragma unroll
  for (int n = 0; n < 8; ++n) {
    const int col = n * 16 + lr;
    bi[n] = bias[col]; gv[n] = g[col]; bv[n] = bb[col];
  }
#pragma unroll
  for (int j = 0; j < 4; ++j) {
    const int gr = rbase + j;
    float x[8];
    float s = 0.f;
#pragma unroll
    for (int n = 0; n < 8; ++n) { x[n] = acc[n][j] + bi[n]; s += x[n]; }
#pragma unroll
    for (int m = 1; m < 16; m <<= 1) s += __shfl_xor(s, m);
    const float mean = s * (1.f / 128.f);
    float v = 0.f;
#pragma unroll
    for (int n = 0; n < 8; ++n) { const float d = x[n] - mean; v += d * d; }
#pragma unroll
    for (int m = 1; m < 16; m <<= 1) v += __shfl_xor(v, m);
    const float rinv = rsqrtf(v * (1.f / 128.f) + 1e-5f);
    if (gr < M) {
#pragma unroll
      for (int n = 0; n < 8; ++n) {
        const int col = n * 16 + lr;
        C[(size_t)gr * 128 + col] = f2b((x[n] - mean) * rinv * gv[n] + bv[n]);
      }
    }
  }
}

// ============ bf16 MFMA GEMM (head): up to 4 segments, generic N, reg-prefetch ============
template<int NSEG, bool RELU>
__global__ __launch_bounds__(256)
void gemm_abf(const ushort* __restrict__ A0, const ushort* __restrict__ A1,
              const ushort* __restrict__ A2, const ushort* __restrict__ A3,
              int Astride, const ushort* __restrict__ Wt, int Ktot,
              const float* __restrict__ bias, ushort* __restrict__ C,
              int Cstride, int M)
{
  __shared__ ushort As[128 * LS];
  __shared__ ushort Bs[128 * LS];
  const int tid = threadIdx.x;
  const int row0 = blockIdx.y << 7;
  const int col0 = blockIdx.x << 7;
  const int l = tid & 63, wid = tid >> 6;
  const int wr = wid >> 1, wc = wid & 1;
  const int lr = l & 15, lkh = l >> 4;
  const int srow = tid >> 2, sq = tid & 3;

  f32x4 acc[4][4];
#pragma unroll
  for (int m = 0; m < 4; ++m)
#pragma unroll
    for (int n = 0; n < 4; ++n) acc[m][n] = (f32x4)0.f;

  const int KT2 = NSEG * 128;
  uint4 pa0, pa1, pb0, pb1;
  auto loadAB = [&](int kk) {
    const int ks = kk >> 7;
    const ushort* Ap = (ks == 0) ? A0 : (ks == 1) ? A1 : (ks == 2) ? A2 : A3;
    const int k0 = kk & 127;
    {
      const int gr = row0 + srow;
      pa0 = make_uint4(0, 0, 0, 0);
      if (gr < M) pa0 = *(const uint4*)(Ap + (size_t)gr * Astride + k0 + sq * 8);
      pb0 = *(const uint4*)(Wt + (size_t)(col0 + srow) * Ktot + kk + sq * 8);
    }
    {
      const int gr = row0 + srow + 64;
      pa1 = make_uint4(0, 0, 0, 0);
      if (gr < M) pa1 = *(const uint4*)(Ap + (size_t)gr * Astride + k0 + sq * 8);
      pb1 = *(const uint4*)(Wt + (size_t)(col0 + srow + 64) * Ktot + kk + sq * 8);
    }
  };

  loadAB(0);
  for (int kk = 0; kk < KT2; kk += 32) {
    *(uint4*)&As[srow * LS + sq * 8] = pa0;
    *(uint4*)&As[(srow + 64) * LS + sq * 8] = pa1;
    *(uint4*)&Bs[srow * LS + sq * 8] = pb0;
    *(uint4*)&Bs[(srow + 64) * LS + sq * 8] = pb1;
    __syncthreads();
    if (kk + 32 < KT2) loadAB(kk + 32);
    bf16x8 af[4], bf[4];
#pragma unroll
    for (int m = 0; m < 4; ++m)
      af[m] = *(const bf16x8*)&As[(wr * 64 + m * 16 + lr) * LS + lkh * 8];
#pragma unroll
    for (int n = 0; n < 4; ++n)
      bf[n] = *(const bf16x8*)&Bs[(wc * 64 + n * 16 + lr) * LS + lkh * 8];
#pragma unroll
    for (int m = 0; m < 4; ++m)
#pragma unroll
      for (int n = 0; n < 4; ++n)
        acc[m][n] = __builtin_amdgcn_mfma_f32_16x16x32_bf16(af[m], bf[n], acc[m][n], 0, 0, 0);
    __syncthreads();
  }

#pragma unroll
  for (int n = 0; n < 4; ++n) {
    const int col = col0 + wc * 64 + n * 16 + lr;
    const float bi = bias[col];
#pragma unroll
    for (int m = 0; m < 4; ++m) {
      const f32x4 v = acc[m][n];
      const int rbase = row0 + wr * 64 + m * 16 + lkh * 4;
#pragma unroll
      for (int j = 0; j < 4; ++j) {
        const int gr = rbase + j;
        if (gr < M) {
          float x = v[j] + bi;
          if (RELU) x = fmaxf(x, 0.f);
          C[(size_t)gr * Cstride + col] = f2b(x);
        }
      }
    }
  }
}

// ============ gather-GEMM: 4 segments with per-row index arrays, reg-prefetch ============
template<bool RELU>
__global__ __launch_bounds__(256)
void gemm_gat4(const ushort* __restrict__ A0, const int* __restrict__ i0,
               const ushort* __restrict__ A1, const int* __restrict__ i1,
               const ushort* __restrict__ A2, const int* __restrict__ i2,
               const ushort* __restrict__ A3,
               const ushort* __restrict__ Wt, const float* __restrict__ bias,
               ushort* __restrict__ C, int Cstride, int M)
{
  __shared__ ushort As[128 * LS];
  __shared__ ushort Bs[128 * LS];
  const int tid = threadIdx.x;
  const int row0 = blockIdx.y << 7;
  const int col0 = blockIdx.x << 7;
  const int l = tid & 63, wid = tid >> 6;
  const int wr = wid >> 1, wc = wid & 1;
  const int lr = l & 15, lkh = l >> 4;
  const int srow = tid >> 2, sq = tid & 3;

  f32x4 acc[4][4];
#pragma unroll
  for (int m = 0; m < 4; ++m)
#pragma unroll
    for (int n = 0; n < 4; ++n) acc[m][n] = (f32x4)0.f;

  uint4 pa0, pa1, pb0, pb1;
  auto loadAB = [&](int kk) {
    const int ks = kk >> 7;
    const ushort* Ap = (ks == 0) ? A0 : (ks == 1) ? A1 : (ks == 2) ? A2 : A3;
    const int* ip = (ks == 0) ? i0 : (ks == 1) ? i1 : (ks == 2) ? i2 : nullptr;
    const int k0 = kk & 127;
    {
      const int gr = row0 + srow;
      pa0 = make_uint4(0, 0, 0, 0);
      if (gr < M) {
        const int ar = ip ? ip[gr] : gr;
        pa0 = *(const uint4*)(Ap + (size_t)ar * 128 + k0 + sq * 8);
      }
      pb0 = *(const uint4*)(Wt + (size_t)(col0 + srow) * 512 + kk + sq * 8);
    }
    {
      const int gr = row0 + srow + 64;
      pa1 = make_uint4(0, 0, 0, 0);
      if (gr < M) {
        const int ar = ip ? ip[gr] : gr;
        pa1 = *(const uint4*)(Ap + (size_t)ar * 128 + k0 + sq * 8);
      }
      pb1 = *(const uint4*)(Wt + (size_t)(col0 + srow + 64) * 512 + kk + sq * 8);
    }
  };

  loadAB(0);
  for (int kk = 0; kk < 512; kk += 32) {
    *(uint4*)&As[srow * LS + sq * 8] = pa0;
    *(uint4*)&As[(srow + 64) * LS + sq * 8] = pa1;
    *(uint4*)&Bs[srow * LS + sq * 8] = pb0;
    *(uint4*)&Bs[(srow + 64) * LS + sq * 8] = pb1;
    __syncthreads();
    if (kk + 32 < 512) loadAB(kk + 32);
    bf16x8 af[4], bf[4];
#pragma unroll
    for (int m = 0; m < 4; ++m)
      af[m] = *(const bf16x8*)&As[(wr * 64 + m * 16 + lr) * LS + lkh * 8];
#pragma unroll
    for (int n = 0; n < 4; ++n)
      bf[n] = *(const bf16x8*)&Bs[(wc * 64 + n * 16 + lr) * LS + lkh * 8];
#pragma unroll
    for (int m = 0; m < 4; ++m)
#pragma unroll
      for (int n = 0; n < 4; ++n)
        acc[m][n] = __builtin_amdgcn_mfma_f32_16x16x32_bf16(af[m], bf[n], acc[m][n], 0, 0, 0);
    __syncthreads();
  }

#pragma unroll
  for (int n = 0; n < 4; ++n) {
    const int col = col0 + wc * 64 + n * 16 + lr;
    const float bi = bias[col];
#pragma unroll
    for (int m = 0; m < 4; ++m) {
      const f32x4 v = acc[m][n];
      const int rbase = row0 + wr * 64 + m * 16 + lkh * 4;
#pragma unroll
      for (int j = 0; j < 4; ++j) {
        const int gr = rbase + j;
        if (gr < M) {
          float x = v[j] + bi;
          if (RELU) x = fmaxf(x, 0.f);
          C[(size_t)gr * Cstride + col] = f2b(x);
        }
      }
    }
  }
}

// ====== fused fp32-A projection GEMMs: 64-row tile, wave = 16x128 strip ======
struct ProjG {
  const float* A[2];
  int Kin[2], Kp[2];
  const ushort* Wt[2];
  const float* bias[2];
  ushort* C[2];
  int M[2];
  int blkStart[3];
};

__global__ __launch_bounds__(256)
void gemm_proj(ProjG pg)
{
  __shared__ ushort As[64 * LS];
  __shared__ ushort Bs[128 * LS];
  const int bid = blockIdx.x;
  const int t = (bid >= pg.blkStart[1]) ? 1 : 0;
  const int row0 = (bid - pg.blkStart[t]) << 6;
  const float* A = pg.A[t];
  const ushort* Wt = pg.Wt[t];
  const int Kin = pg.Kin[t], Kp = pg.Kp[t], M = pg.M[t];
  const int tid = threadIdx.x;
  const int l = tid & 63, wid = tid >> 6;
  const int lr = l & 15, lkh = l >> 4;
  const int arow = tid >> 2, aq = tid & 3;

  f32x4 acc[8];
#pragma unroll
  for (int n = 0; n < 8; ++n) acc[n] = (f32x4)0.f;

  float4 pfa0, pfa1;
  uint4 pw0, pw1;
  auto loadP = [&](int kk) {
    const int gk = kk + aq * 8;
    const int gr = row0 + arow;
    float4 f0 = make_float4(0.f, 0.f, 0.f, 0.f), f1 = f0;
    if (gr < M) {
      const float* ap = A + (size_t)gr * Kin + gk;
      if (gk + 7 < Kin) { f0 = *(const float4*)ap; f1 = *(const float4*)(ap + 4); }
      else {
        float tv[8];
#pragma unroll
        for (int j = 0; j < 8; ++j) tv[j] = (gk + j < Kin) ? ap[j] : 0.f;
        f0 = make_float4(tv[0], tv[1], tv[2], tv[3]);
        f1 = make_float4(tv[4], tv[5], tv[6], tv[7]);
      }
    }
    pfa0 = f0; pfa1 = f1;
    pw0 = *(const uint4*)(Wt + (size_t)arow * Kp + kk + aq * 8);
    pw1 = *(const uint4*)(Wt + (size_t)(arow + 64) * Kp + kk + aq * 8);
  };

  loadP(0);
  for (int kk = 0; kk < Kp; kk += 32) {
    {
      uint4 w;
      w.x = f2b(pfa0.x) | ((uint)f2b(pfa0.y) << 16);
      w.y = f2b(pfa0.z) | ((uint)f2b(pfa0.w) << 16);
      w.z = f2b(pfa1.x) | ((uint)f2b(pfa1.y) << 16);
      w.w = f2b(pfa1.z) | ((uint)f2b(pfa1.w) << 16);
      *(uint4*)&As[arow * LS + aq * 8] = w;
      *(uint4*)&Bs[arow * LS + aq * 8] = pw0;
      *(uint4*)&Bs[(arow + 64) * LS + aq * 8] = pw1;
    }
    __syncthreads();
    if (kk + 32 < Kp) loadP(kk + 32);
    const bf16x8 af = *(const bf16x8*)&As[(wid * 16 + lr) * LS + lkh * 8];
    bf16x8 bf[8];
#pragma unroll
    for (int n = 0; n < 8; ++n)
      bf[n] = *(const bf16x8*)&Bs[(n * 16 + lr) * LS + lkh * 8];
#pragma unroll
    for (int n = 0; n < 8; ++n)
      acc[n] = __builtin_amdgcn_mfma_f32_16x16x32_bf16(af, bf[n], acc[n], 0, 0, 0);
    __syncthreads();
  }

  const float* bias = pg.bias[t];
  ushort* C = pg.C[t];
  const int rbase = row0 + wid * 16 + lkh * 4;
#pragma unroll
  for (int n = 0; n < 8; ++n) {
    const int col = n * 16 + lr;
    const float bi = bias[col];
    const f32x4 v = acc[n];
#pragma unroll
    for (int j = 0; j < 4; ++j) {
      const int gr = rbase + j;
      if (gr < M) C[(size_t)gr * 128 + col] = f2b(v[j] + bi);
    }
  }
}

// ================= weight conversion =================
__global__ void conv_wt(const float* __restrict__ W, ushort* __restrict__ Wt,
                        int K, int N, int Kp)
{
  const int kp = blockIdx.x * 256 + threadIdx.x;
  const int n = blockIdx.y;
  if (kp >= Kp) return;
  const float v = (kp < K) ? W[(size_t)kp * N + n] : 0.f;
  Wt[(size_t)n * Kp + kp] = f2b(v);
}

__global__ void conv_wcat(const float* __restrict__ Wl, const float* __restrict__ bl,
                          const float* __restrict__ Wr, const float* __restrict__ br,
                          ushort* __restrict__ WC, float* __restrict__ BC)
{
  const int KT[5]   = {512, 384, 256, 256, 256};
  const int TOFF[5] = {0, 512 * 128, 896 * 128, 1152 * 128, 1408 * 128};
  const int RL[5][3] = {{0, 4, 7}, {1, 2, -1}, {3, -1, -1}, {5, -1, -1}, {6, -1, -1}};
  const int NS[5] = {3, 2, 1, 1, 1};
  const int lt = blockIdx.y;
  const int lay = lt / 5, tt = lt % 5;
  const int idx = blockIdx.x * 256 + threadIdx.x;
  const int kk = idx >> 7, n = idx & 127;
  const int Kt = KT[tt];
  ushort* w = WC + (size_t)lay * (1664 * 128) + TOFF[tt] + (size_t)n * Kt;
  float s = 0.f;
  for (int q = 0; q < NS[tt]; ++q) {
    const int r = RL[tt][q];
    s += Wr[((size_t)lay * 8 + r) * 16384 + kk * 128 + n];
    w[(q + 1) * 128 + kk] = f2b(Wl[((size_t)lay * 8 + r) * 16384 + kk * 128 + n]);
  }
  w[kk] = f2b(s);
  if (kk == 0) {
    float b = 0.f;
    for (int q = 0; q < NS[tt]; ++q) {
      const int r = RL[tt][q];
      b += bl[(lay * 8 + r) * 128 + n] + br[(lay * 8 + r) * 128 + n];
    }
    BC[lt * 128 + n] = b;
  }
}

// head weight fold: WH[256][512]; seg0..2 = v_W1^T, seg3 = (xo_W @ v_W1[384:])^T
__global__ void conv_head(const float* __restrict__ vW1, const float* __restrict__ vb1,
                          const float* __restrict__ xoW, const float* __restrict__ xob,
                          ushort* __restrict__ WH, float* __restrict__ BH)
{
  const int idx = blockIdx.x * 256 + threadIdx.x;   // 256*512
  const int n = idx >> 9, k = idx & 511;
  if (k < 384) {
    WH[(size_t)n * 512 + k] = f2b(vW1[(size_t)k * 256 + n]);
  } else {
    const int c = k - 384;
    float s = 0.f;
    for (int d = 0; d < 128; ++d)
      s += xoW[c * 128 + d] * vW1[(size_t)(384 + d) * 256 + n];
    WH[(size_t)n * 512 + k] = f2b(s);
    if (c == 0) {
      float bb = vb1[n];
      for (int d = 0; d < 128; ++d)
        bb += xob[d] * vW1[(size_t)(384 + d) * 256 + n];
      BH[n] = bb;
    }
  }
}

__global__ void concat_bias2(const float* __restrict__ a, const float* __restrict__ b,
                             float* __restrict__ o)
{
  const int i = threadIdx.x;
  o[i] = (i < 128) ? a[i] : b[i - 128];
}

__global__ void conv_f2b_kernel(const float* __restrict__ in, ushort* __restrict__ out, int n)
{
  const int i = blockIdx.x * 256 + threadIdx.x;
  if (i < n) out[i] = f2b(in[i]);
}

// ================= small projection MLPs (bf16 out) =================
__global__ void proj_lt_kernel(const float* __restrict__ X, const float* __restrict__ W1,
                               const float* __restrict__ b1, const float* __restrict__ W2,
                               const float* __restrict__ b2, ushort* __restrict__ Y, int n)
{
  __shared__ float xs[4];
  __shared__ float hid[64];
  const int node = blockIdx.x, tid = threadIdx.x;
  if (node >= n) return;
  if (tid < 4) xs[tid] = X[(size_t)node * 4 + tid];
  __syncthreads();
  if (tid < 64) {
    float a = b1[tid];
#pragma unroll
    for (int k = 0; k < 4; ++k) a += xs[k] * W1[k * 64 + tid];
    hid[tid] = fmaxf(a, 0.f);
  }
  __syncthreads();
  float o = b2[tid];
  for (int k = 0; k < 64; ++k) o += hid[k] * W2[k * 128 + tid];
  Y[(size_t)node * 128 + tid] = f2b(o);
}

__global__ void proj_comm_kernel(const float* __restrict__ X, const float* __restrict__ W1,
                                 const float* __restrict__ b1, const float* __restrict__ W2,
                                 const float* __restrict__ b2, ushort* __restrict__ Y, int n)
{
  __shared__ float xs[65];
  __shared__ float hid[128];
  const int node = blockIdx.x, tid = threadIdx.x;
  if (node >= n) return;
  if (tid < 65) xs[tid] = X[(size_t)node * 65 + tid];
  __syncthreads();
  float a = b1[tid];
  for (int k = 0; k < 65; ++k) a += xs[k] * W1[k * 128 + tid];
  hid[tid] = fmaxf(a, 0.f);
  __syncthreads();
  float o = b2[tid];
  for (int k = 0; k < 128; ++k) o += hid[k] * W2[k * 128 + tid];
  Y[(size_t)node * 128 + tid] = f2b(o);
}

// ================= fused CSR build =================
struct EdgesAll {
  const int* src[8];
  const int* dst[8];
  int estart[9];
  int f9off[8];
};

__global__ void hist_all(EdgesAll ea, int* __restrict__ deg)
{
  const int e = blockIdx.x * 256 + threadIdx.x;
  if (e >= ea.estart[8]) return;
  int r = 0;
  while (e >= ea.estart[r + 1]) ++r;
  const int el = e - ea.estart[r];
  atomicAdd(&deg[ea.f9off[r] + ea.dst[r][el]], 1);
}

__global__ void fill_all(EdgesAll ea, const int* __restrict__ rp,
                         int* __restrict__ cur, int2* __restrict__ col)
{
  const int e = blockIdx.x * 256 + threadIdx.x;
  if (e >= ea.estart[8]) return;
  int r = 0;
  while (e >= ea.estart[r + 1]) ++r;
  const int el = e - ea.estart[r];
  const int d = ea.f9off[r] + ea.dst[r][el];
  const int p = atomicAdd(&cur[d], 1);
  col[rp[d] + p] = make_int2(ea.src[r][el], el);
}

__global__ __launch_bounds__(256)
void scan_blk(const int* __restrict__ in, int* __restrict__ out,
              int* __restrict__ bsum, int n)
{
  __shared__ int wsum[4];
  const int t = threadIdx.x;
  const int base = blockIdx.x * 1024 + t * 4;
  const int v0 = (base + 0 < n) ? in[base + 0] : 0;
  const int v1 = (base + 1 < n) ? in[base + 1] : 0;
  const int v2 = (base + 2 < n) ? in[base + 2] : 0;
  const int v3 = (base + 3 < n) ? in[base + 3] : 0;
  const int s = v0 + v1 + v2 + v3;
  const int lane = t & 63;
  int incl = s;
#pragma unroll
  for (int m = 1; m < 64; m <<= 1) {
    const int o = __shfl_up(incl, m);
    if (lane >= m) incl += o;
  }
  const int wid = t >> 6;
  if (lane == 63) wsum[wid] = incl;
  __syncthreads();
  int woff = 0;
#pragma unroll
  for (int w = 0; w < 3; ++w) woff += (w < wid) ? wsum[w] : 0;
  int run = woff + incl - s;
  if (base + 0 < n) out[base + 0] = run; run += v0;
  if (base + 1 < n) out[base + 1] = run; run += v1;
  if (base + 2 < n) out[base + 2] = run; run += v2;
  if (base + 3 < n) out[base + 3] = run;
  if (bsum != nullptr && t == 255) bsum[blockIdx.x] = woff + incl;
}

__global__ void scan_add(int* __restrict__ rp, const int* __restrict__ bsum, int n)
{
  const int i = blockIdx.x * 1024 + threadIdx.x * 4;
  const int add = bsum[blockIdx.x];
#pragma unroll
  for (int k = 0; k < 4; ++k)
    if (i + k < n) rp[i + k] += add;
}

// ======== F9: ONE THREAD per node (deg is tiny); r6 handled by f9_topic ========
struct F9All {
  const float* tt[8];
  int f9off[9];
};

__global__ __launch_bounds__(256)
void f9_thread(F9All fa, const int2* __restrict__ col, const int* __restrict__ rp,
               const float* __restrict__ w0p, const float* __restrict__ b0p,
               const float* __restrict__ wkp, const float* __restrict__ bkp,
               float* __restrict__ F9)
{
  const int node = blockIdx.x * 256 + threadIdx.x;
  if (node >= F9TOT) return;
  float* fo = F9 + (size_t)node * 9;
  if (node >= 312000 && node < 312115) {   // r6 range: zero (f9_topic accumulates)
#pragma unroll
    for (int k = 0; k < 9; ++k) fo[k] = 0.f;
    return;
  }
  int r = 0;
  while (node >= fa.f9off[r + 1]) ++r;
  const float* tvals = fa.tt[r];
  const int e0 = rp[node], e1 = rp[node + 1];
  const float w0 = w0p[0], b0 = b0p[0];
  float wk[8], bk[8];
#pragma unroll
  for (int k = 0; k < 8; ++k) { wk[k] = wkp[k]; bk[k] = bkp[k]; }
  float st = 0.f;
  float fk[8];
#pragma unroll
  for (int k = 0; k < 8; ++k) fk[k] = 0.f;
  for (int e = e0; e < e1; ++e) {
    const float tv = tvals[col[e].y];
    st += tv;
#pragma unroll
    for (int k = 0; k < 8; ++k) fk[k] += __sinf(tv * wk[k] + bk[k]);
  }
  fo[0] = st * w0 + (float)(e1 - e0) * b0;
#pragma unroll
  for (int k = 0; k < 8; ++k) fo[1 + k] = fk[k];
}

// r6 (topic, deg~435): 64 threads per node, local sums then 9 atomics each
__global__ void f9_topic(const int2* __restrict__ col, const int* __restrict__ rp,
                         const float* __restrict__ tvals,
                         const float* __restrict__ w0p, const float* __restrict__ b0p,
                         const float* __restrict__ wkp, const float* __restrict__ bkp,
                         float* __restrict__ F9)
{
  const int t = blockIdx.x * 256 + threadIdx.x;
  if (t >= cNT * 64) return;
  const int node = t >> 6, j = t & 63;
  const int e0 = rp[node], e1 = rp[node + 1];
  const float w0 = w0p[0], b0 = b0p[0];
  float wk[8], bk[8];
#pragma unroll
  for (int k = 0; k < 8; ++k) { wk[k] = wkp[k]; bk[k] = bkp[k]; }
  float st = 0.f;
  float fk[8];
#pragma unroll
  for (int k = 0; k < 8; ++k) fk[k] = 0.f;
  int cnt = 0;
  for (int e = e0 + j; e < e1; e += 64) {
    const float tv = tvals[col[e].y];
    st += tv; ++cnt;
#pragma unroll
    for (int k = 0; k < 8; ++k) fk[k] += __sinf(tv * wk[k] + bk[k]);
  }
  float* fo = F9 + (size_t)node * 9;
  atomicAdd(fo, st * w0 + (float)cnt * b0);
#pragma unroll
  for (int k = 0; k < 8; ++k) atomicAdd(fo + 1 + k, fk[k]);
}

// ======== fused per-layer gather: QUARTER-WAVE per node, uint4 rows ========
constexpr int QW_SPLIT0 = 312000;             // nodes before rel6 split section
constexpr int QW_SPLIT1 = 312000 + 115 * 64;  // end of split section
constexpr int QW_TOTAL  = QW_SPLIT1 + 50000;  // + rel7 nodes

struct GatherAll {
  const ushort* Hsrc[8];
  const float* eW;      // edge_W base
  const float* eb;      // edge_b base
  const int2* col;
  const int* rp;
  const float* F9;
  ushort* S;
  float* SPtop;
  int f9off[7];   // {0,50000,150000,250000,260000,310000,312000}
};

__global__ __launch_bounds__(256)
void gather_all(GatherAll ga)
{
  const int qw = (blockIdx.x * 256 + threadIdx.x) >> 4;
  if (qw >= QW_TOTAL) return;
  const int lq = threadIdx.x & 15;
  int node, r, splitj = -1;
  if (qw < QW_SPLIT0) {
    node = qw;
    r = 0;
    while (node >= ga.f9off[r + 1]) ++r;     // r in 0..5
  } else if (qw < QW_SPLIT1) {
    const int lw = qw - QW_SPLIT0;
    node = QW_SPLIT0 + (lw >> 6);
    splitj = lw & 63;
    r = 6;
  } else {
    node = 312115 + (qw - QW_SPLIT1);
    r = 7;
  }
  const int e0 = ga.rp[node], e1 = ga.rp[node + 1];
  const uint4* H4 = (const uint4*)ga.Hsrc[r];
  float a[8];
#pragma unroll
  for (int i = 0; i < 8; ++i) a[i] = 0.f;

#define ACC8(v)                                              \
  { a[0] += b2f((ushort)(v).x); a[1] += b2f((ushort)((v).x >> 16)); \
    a[2] += b2f((ushort)(v).y); a[3] += b2f((ushort)((v).y >> 16)); \
    a[4] += b2f((ushort)(v).z); a[5] += b2f((ushort)((v).z >> 16)); \
    a[6] += b2f((ushort)(v).w); a[7] += b2f((ushort)((v).w >> 16)); }

  if (splitj >= 0) {
    int e = e0 + splitj;
    for (; e + 64 < e1; e += 128) {
      const int s0 = ga.col[e].x, s1 = ga.col[e + 64].x;
      const uint4 v0 = H4[(size_t)s0 * 16 + lq];
      const uint4 v1 = H4[(size_t)s1 * 16 + lq];
      ACC8(v0); ACC8(v1);
    }
    if (e < e1) { const uint4 v = H4[(size_t)ga.col[e].x * 16 + lq]; ACC8(v); }
    float* p = &ga.SPtop[(size_t)(node - QW_SPLIT0) * 128 + lq * 8];
#pragma unroll
    for (int i = 0; i < 8; ++i) atomicAdd(p + i, a[i]);
    return;
  }
  int e = e0;
  for (; e + 3 < e1; e += 4) {
    const int s0 = ga.col[e].x, s1 = ga.col[e + 1].x;
    const int s2 = ga.col[e + 2].x, s3 = ga.col[e + 3].x;
    const uint4 v0 = H4[(size_t)s0 * 16 + lq];
    const uint4 v1 = H4[(size_t)s1 * 16 + lq];
    const uint4 v2 = H4[(size_t)s2 * 16 + lq];
    const uint4 v3 = H4[(size_t)s3 * 16 + lq];
    ACC8(v0); ACC8(v1); ACC8(v2); ACC8(v3);
  }
  if (e + 1 < e1) {
    const int s0 = ga.col[e].x, s1 = ga.col[e + 1].x;
    const uint4 v0 = H4[(size_t)s0 * 16 + lq];
    const uint4 v1 = H4[(size_t)s1 * 16 + lq];
    ACC8(v0); ACC8(v1);
    e += 2;
  }
  if (e < e1) { const uint4 v = H4[(size_t)ga.col[e].x * 16 + lq]; ACC8(v); }

  const float* eW = ga.eW + (size_t)r * 9 * 128;
  const float* eb = ga.eb + (size_t)r * 128;
  float f9[9];
#pragma unroll
  for (int k = 0; k < 9; ++k) f9[k] = ga.F9[(size_t)node * 9 + k];
  const int degn = e1 - e0;
  const int j0 = lq * 8;
#pragma unroll
  for (int k = 0; k < 9; ++k) {
#pragma unroll
    for (int i = 0; i < 8; ++i) a[i] += f9[k] * eW[k * 128 + j0 + i];
  }
  const float rinv = 1.f / fmaxf((float)degn, 1.f);
#pragma unroll
  for (int i = 0; i < 8; ++i) a[i] *= rinv;
  if (degn > 0) {
#pragma unroll
    for (int i = 0; i < 8; ++i) a[i] += eb[j0 + i];
  }
  uint4 o;
  o.x = (uint)f2b(a[0]) | ((uint)f2b(a[1]) << 16);
  o.y = (uint)f2b(a[2]) | ((uint)f2b(a[3]) << 16);
  o.z = (uint)f2b(a[4]) | ((uint)f2b(a[5]) << 16);
  o.w = (uint)f2b(a[6]) | ((uint)f2b(a[7]) << 16);
  ((uint4*)ga.S)[(size_t)node * 16 + lq] = o;
#undef ACC8
}

__global__ void finalize_split(const float* __restrict__ SP, const int* __restrict__ rp,
                               const float* __restrict__ F9, const float* __restrict__ eW,
                               const float* __restrict__ eb, ushort* __restrict__ S, int nd)
{
  const int gw = (blockIdx.x * blockDim.x + threadIdx.x) >> 6;
  if (gw >= nd) return;
  const int lane = threadIdx.x & 63;
  const int degn = rp[gw + 1] - rp[gw];
  const int j = lane * 2;
  const float2 sv = *(const float2*)&SP[(size_t)gw * 128 + j];
  float f9[9];
#pragma unroll
  for (int k = 0; k < 9; ++k) f9[k] = F9[(size_t)gw * 9 + k];
  float o0 = sv.x, o1 = sv.y;
#pragma unroll
  for (int k = 0; k < 9; ++k) {
    o0 += f9[k] * eW[k * 128 + j];
    o1 += f9[k] * eW[k * 128 + j + 1];
  }
  const float rinv = 1.f / fmaxf((float)degn, 1.f);
  o0 *= rinv; o1 *= rinv;
  if (degn > 0) { o0 += eb[j]; o1 += eb[j + 1]; }
  ((uint*)S)[(size_t)gw * 64 + lane] = (uint)f2b(o0) | ((uint)f2b(o1) << 16);
}

// ======== h_bill: quarter-wave per node, uint4 rows ========
__global__ __launch_bounds__(256)
void gather_bill(const ushort* __restrict__ H1, const int2* __restrict__ col,
                 const int* __restrict__ rp, const ushort* __restrict__ H0,
                 ushort* __restrict__ S, int nB)
{
  const int qw = (blockIdx.x * 256 + threadIdx.x) >> 4;
  if (qw >= nB) return;
  const int lq = threadIdx.x & 15;
  const int e0 = rp[qw], e1 = rp[qw + 1];
  const uint4* H14 = (const uint4*)H1;
  float a[8];
#pragma unroll
  for (int i = 0; i < 8; ++i) a[i] = 0.f;
#define ACC8(v)                                              \
  { a[0] += b2f((ushort)(v).x); a[1] += b2f((ushort)((v).x >> 16)); \
    a[2] += b2f((ushort)(v).y); a[3] += b2f((ushort)((v).y >> 16)); \
    a[4] += b2f((ushort)(v).z); a[5] += b2f((ushort)((v).z >> 16)); \
    a[6] += b2f((ushort)(v).w); a[7] += b2f((ushort)((v).w >> 16)); }
  int e = e0;
  for (; e + 1 < e1; e += 2) {
    const int s0 = col[e].x, s1 = col[e + 1].x;
    const uint4 v0 = H14[(size_t)s0 * 16 + lq];
    const uint4 v1 = H14[(size_t)s1 * 16 + lq];
    ACC8(v0); ACC8(v1);
  }
  if (e < e1) { const uint4 v = H14[(size_t)col[e].x * 16 + lq]; ACC8(v); }
#undef ACC8
  const float rc = 1.f / ((float)(e1 - e0) + 1e-6f);
  const uint4 h0 = ((const uint4*)H0)[(size_t)qw * 16 + lq];
  uint4 o;
  o.x = (uint)f2b(0.5f * b2f((ushort)h0.x) + 0.5f * a[0] * rc)
      | ((uint)f2b(0.5f * b2f((ushort)(h0.x >> 16)) + 0.5f * a[1] * rc) << 16);
  o.y = (uint)f2b(0.5f * b2f((ushort)h0.y) + 0.5f * a[2] * rc)
      | ((uint)f2b(0.5f * b2f((ushort)(h0.y >> 16)) + 0.5f * a[3] * rc) << 16);
  o.z = (uint)f2b(0.5f * b2f((ushort)h0.z) + 0.5f * a[4] * rc)
      | ((uint)f2b(0.5f * b2f((ushort)(h0.z >> 16)) + 0.5f * a[5] * rc) << 16);
  o.w = (uint)f2b(0.5f * b2f((ushort)h0.w) + 0.5f * a[6] * rc)
      | ((uint)f2b(0.5f * b2f((ushort)(h0.w >> 16)) + 0.5f * a[7] * rc) << 16);
  ((uint4*)S)[(size_t)qw * 16 + lq] = o;
}

// ================= per-vote softmax attention (1 wave/vote) =================
__global__ __launch_bounds__(256)
void attn_lite(const ushort* __restrict__ Ql, const ushort* __restrict__ KVb,
               const int* __restrict__ vote_lt, const int* __restrict__ vote_bv,
               const int* __restrict__ isv_dst, const int* __restrict__ t_for_bill,
               ushort* __restrict__ CT, int* __restrict__ tpv, int nV)
{
  const int gw = (blockIdx.x * blockDim.x + threadIdx.x) >> 6;
  if (gw >= nV) return;
  const int lane = threadIdx.x & 63;
  const int bv = vote_bv[gw];
  const int lt = vote_lt[gw];
  const int b = isv_dst[bv];
  if (lane == 0) tpv[gw] = t_for_bill[b];
  const uint q  = ((const uint*)Ql)[(size_t)lt * 64 + lane];
  const uint kk = ((const uint*)KVb)[(size_t)b * 128 + lane];
  const uint vv = ((const uint*)KVb)[(size_t)b * 128 + 64 + lane];
  const float q0 = b2f((ushort)q),  q1 = b2f((ushort)(q >> 16));
  const float k0 = b2f((ushort)kk), k1 = b2f((ushort)(kk >> 16));
  float s = q0 * k0 + q1 * k1;
#pragma unroll
  for (int m = 1; m < 16; m <<= 1) s += __shfl_xor(s, m);   // 16-lane head groups
  s *= 0.17677669529663687f;                                // 1/sqrt(32)
  float mx = fmaxf(s, __shfl_xor(s, 16));
  mx = fmaxf(mx, __shfl_xor(mx, 32));
  const float e = __expf(s - mx);
  float den = e + __shfl_xor(e, 16);
  den += __shfl_xor(den, 32);
  const float a = e / den;
  const float v0f = b2f((ushort)vv), v1f = b2f((ushort)(vv >> 16));
  ((uint*)CT)[(size_t)gw * 64 + lane] =
      (uint)f2b(a * v0f) | ((uint)f2b(a * v1f) << 16);
}

// ================= final 128 -> 3 (bf16 G) =================
__global__ void final_out(const ushort* __restrict__ G, const float* __restrict__ Wo,
                          const float* __restrict__ bo, float* __restrict__ out,
                          int v0, int nV)
{
  const int wave = (blockIdx.x * blockDim.x + threadIdx.x) >> 6;
  const int lane = threadIdx.x & 63;
  if (wave >= nV) return;
  const ushort* g = G + (size_t)wave * 128;
  const float x0 = b2f(g[lane]), x1 = b2f(g[64 + lane]);
  float s0 = x0 * Wo[lane * 3 + 0] + x1 * Wo[(64 + lane) * 3 + 0];
  float s1 = x0 * Wo[lane * 3 + 1] + x1 * Wo[(64 + lane) * 3 + 1];
  float s2 = x0 * Wo[lane * 3 + 2] + x1 * Wo[(64 + lane) * 3 + 2];
#pragma unroll
  for (int m = 1; m < 64; m <<= 1) {
    s0 += __shfl_xor(s0, m);
    s1 += __shfl_xor(s1, m);
    s2 += __shfl_xor(s2, m);
  }
  if (lane == 0) {
    float* o = out + (size_t)(v0 + wave) * 3;
    o[0] = s0 + bo[0]; o[1] = s1 + bo[1]; o[2] = s2 + bo[2];
  }
}

// ================= host side =================
static inline int cdiv(int a, int b) { return (a + b - 1) / b; }

extern "C" void kernel_launch(void* const* d_in, const int* in_sizes, int n_in,
                              void* d_out, int out_size, void* d_ws, size_t ws_size,
                              hipStream_t stream)
{
  (void)in_sizes; (void)n_in; (void)out_size;

  const float* x_bill = (const float*)d_in[0];
  const float* x_bv   = (const float*)d_in[1];
  const float* x_lt   = (const float*)d_in[2];
  const float* x_comm = (const float*)d_in[3];
  const float* pb_W  = (const float*)d_in[4];
  const float* pb_b  = (const float*)d_in[5];
  const float* pbv_W = (const float*)d_in[6];
  const float* pbv_b = (const float*)d_in[7];
  const float* plt_W1 = (const float*)d_in[8];
  const float* plt_b1 = (const float*)d_in[9];
  const float* plt_W2 = (const float*)d_in[10];
  const float* plt_b2 = (const float*)d_in[11];
  const float* pc_W1 = (const float*)d_in[12];
  const float* pc_b1 = (const float*)d_in[13];
  const float* pc_W2 = (const float*)d_in[14];
  const float* pc_b2 = (const float*)d_in[15];
  const float* topic_emb = (const float*)d_in[16];
  const float* t2v_w0 = (const float*)d_in[17];
  const float* t2v_b0 = (const float*)d_in[18];
  const float* t2v_wk = (const float*)d_in[19];
  const float* t2v_bk = (const float*)d_in[20];
  const float* edge_W = (const float*)d_in[21];
  const float* edge_b = (const float*)d_in[22];
  const float* sage_Wl = (const float*)d_in[23];
  const float* sage_bl = (const float*)d_in[24];
  const float* sage_Wr = (const float*)d_in[25];
  const float* sage_br = (const float*)d_in[26];
  const float* ln_g = (const float*)d_in[27];
  const float* ln_b = (const float*)d_in[28];
  const float* xq_W = (const float*)d_in[29];
  const float* xq_b = (const float*)d_in[30];
  const float* xk_W = (const float*)d_in[31];
  const float* xk_b = (const float*)d_in[32];
  const float* xv_W = (const float*)d_in[33];
  const float* xv_b = (const float*)d_in[34];
  const float* xo_W = (const float*)d_in[35];
  const float* xo_b = (const float*)d_in[36];
  const float* v_W1 = (const float*)d_in[37];
  const float* v_b1 = (const float*)d_in[38];
  const float* v_W2 = (const float*)d_in[39];
  const float* v_b2 = (const float*)d_in[40];
  const float* v_Wo = (const float*)d_in[41];
  const float* v_bo = (const float*)d_in[42];
  const float* t_isv   = (const float*)d_in[43];
  const float* t_vote  = (const float*)d_in[44];
  const float* t_rev   = (const float*)d_in[45];
  const float* t_about = (const float*)d_in[46];
  const int* ei_isv   = (const int*)d_in[47];
  const int* ei_vote  = (const int*)d_in[48];
  const int* ei_rev   = (const int*)d_in[49];
  const int* ei_about = (const int*)d_in[50];
  const int* t_for_bill = (const int*)d_in[51];
  const int* vote_lt = (const int*)d_in[52];
  const int* vote_bv = (const int*)d_in[53];
  float* out = (float*)d_out;

  const int OFFS[5] = {0, cNB, cNB + cNBV, cNB + cNBV + cNLT, cNB + cNBV + cNLT + cNC};
  const int NSZ[5]  = {cNB, cNBV, cNLT, cNC, cNT};

  // -------- workspace layout (bytes) --------
  char* w = (char*)d_ws;
  const size_t szHb = (size_t)cNTOT * 128 * 2;            // 41.5 MB
  const size_t szS  = (size_t)F9TOT * 128 * 2;            // 92.7 MB
  ushort* Hb   = (ushort*)w;                              // ping
  ushort* Hh2  = (ushort*)(w + szHb);                     // pong
  ushort* Sall = (ushort*)(w + 2 * szHb);
  size_t off = 2 * szHb + szS;
  ushort* WT_pb  = (ushort*)(w + off); off += (size_t)128 * 800 * 2;
  ushort* WT_pbv = (ushort*)(w + off); off += (size_t)128 * 416 * 2;
  ushort* WC     = (ushort*)(w + off); off += (size_t)3 * 1664 * 128 * 2;
  ushort* WT_v2  = (ushort*)(w + off); off += (size_t)128 * 256 * 2;
  ushort* WT_q   = (ushort*)(w + off); off += (size_t)128 * 128 * 2;
  ushort* WT_kv  = (ushort*)(w + off); off += (size_t)256 * 128 * 2;
  ushort* WH     = (ushort*)(w + off); off += (size_t)256 * 512 * 2;
  off = (off + 15) & ~(size_t)15;
  float* BC  = (float*)(w + off); off += (size_t)15 * 128 * 4;
  float* BH  = (float*)(w + off); off += (size_t)256 * 4;
  float* BKV = (float*)(w + off); off += (size_t)256 * 4;
  float* SPtop = (float*)(w + off); off += (size_t)cNT * 128 * 4;   // dedicated
  int* rp = (int*)(w + off); off += (size_t)(F9TOT + 1) * 4;
  off = (off + 7) & ~(size_t)7;
  int2* col = (int2*)(w + off); off += (size_t)ETOT * 8;
  float* F9 = (float*)(w + off); off += (size_t)F9TOT * 9 * 4;   // 13.0 MB
  int* tpv = (int*)(w + off); off += (size_t)cNVOTE * 4;
  if (ws_size < off) return;

  // transients aliased into Sall (dead before first gather use)
  int* deg  = (int*)Sall;
  int* cur  = deg + (F9TOT + 1);
  int* bsum = cur + F9TOT;
  // post-layer aliases: Sall holds hbill_b | CT | KVb | Ql  (66.6 MB <= 92.7)
  ushort* hbill_b = Sall;                                         // 50000*128
  ushort* CT  = Sall + (size_t)cNB * 128;                         // 100000*128
  ushort* KVb = CT + (size_t)cNVOTE * 128;                        // 50000*256
  ushort* Ql  = KVb + (size_t)cNB * 256;                          // 10000*128
  // head scratch aliases Hb (dead after last layer reads it): Uc | Gc
  ushort* Uc = Hb;                                                // 50000*256
  ushort* Gc = Hb + (size_t)50000 * 256;                          // 50000*128

  // relation tables
  const int F9OFF[9] = {0, 50000, 150000, 250000, 260000, 310000, 312000, 312115, 362115};
  const int ESTART[9] = {0, 100000, 200000, 600000, 1000000, 1050000, 1100000, 1150000, 1200000};
  const int SRCT[8] = {1, 0, 2, 1, 3, 0, 0, 4};
  const int* rel_src[8] = {ei_isv, ei_isv + cNBV, ei_vote, ei_vote + cEV,
                           ei_rev, ei_rev + cER, ei_about, ei_about + cNB};
  const int* rel_dst[8] = {ei_isv + cNBV, ei_isv, ei_vote + cEV, ei_vote,
                           ei_rev + cER, ei_rev, ei_about + cNB, ei_about};
  const float* rel_tt[8] = {t_isv, t_isv, t_vote, t_vote, t_rev, t_rev, t_about, t_about};

  // ---- 0. weight conversions ----
  conv_wt<<<dim3(4, 128), 256, 0, stream>>>(pb_W, WT_pb, 770, 128, 800);
  conv_wt<<<dim3(2, 128), 256, 0, stream>>>(pbv_W, WT_pbv, 390, 128, 416);
  conv_wt<<<dim3(1, 128), 256, 0, stream>>>(v_W2, WT_v2, 256, 128, 256);
  conv_wt<<<dim3(1, 128), 256, 0, stream>>>(xq_W, WT_q, 128, 128, 128);
  conv_wt<<<dim3(1, 128), 256, 0, stream>>>(xk_W, WT_kv, 128, 128, 128);
  conv_wt<<<dim3(1, 128), 256, 0, stream>>>(xv_W, WT_kv + 128 * 128, 128, 128, 128);
  conv_head<<<512, 256, 0, stream>>>(v_W1, v_b1, xo_W, xo_b, WH, BH);
  concat_bias2<<<1, 256, 0, stream>>>(xk_b, xv_b, BKV);
  conv_wcat<<<dim3(64, 15), 256, 0, stream>>>(sage_Wl, sage_bl, sage_Wr, sage_br, WC, BC);
  conv_f2b_kernel<<<cdiv(cNT * 128, 256), 256, 0, stream>>>(
      topic_emb, Hb + (size_t)OFFS[4] * 128, cNT * 128);

  // ---- 1. CSR build (fused) ----
  EdgesAll ea;
  for (int r = 0; r < 8; ++r) {
    ea.src[r] = rel_src[r]; ea.dst[r] = rel_dst[r]; ea.f9off[r] = F9OFF[r];
  }
  for (int r = 0; r < 9; ++r) ea.estart[r] = ESTART[r];
  const int nScan = F9TOT + 1;
  const int nb = cdiv(nScan, 1024);
  hipMemsetAsync(deg, 0, (size_t)nScan * sizeof(int), stream);
  hist_all<<<cdiv(ETOT, 256), 256, 0, stream>>>(ea, deg);
  scan_blk<<<nb, 256, 0, stream>>>(deg, rp, bsum, nScan);
  scan_blk<<<1, 256, 0, stream>>>(bsum, bsum, nullptr, nb);
  scan_add<<<nb, 256, 0, stream>>>(rp, bsum, nScan);
  hipMemsetAsync(cur, 0, (size_t)F9TOT * sizeof(int), stream);
  fill_all<<<cdiv(ETOT, 256), 256, 0, stream>>>(ea, rp, cur, col);

  // ---- 1b. F9 precompute (thread-per-node + topic split) ----
  F9All fa;
  for (int r = 0; r < 8; ++r) fa.tt[r] = rel_tt[r];
  for (int r = 0; r < 9; ++r) fa.f9off[r] = F9OFF[r];
  f9_thread<<<cdiv(F9TOT, 256), 256, 0, stream>>>(
      fa, col, rp, t2v_w0, t2v_b0, t2v_wk, t2v_bk, F9);
  f9_topic<<<cdiv(cNT * 64, 256), 256, 0, stream>>>(
      col, rp + F9OFF[6], t_about, t2v_w0, t2v_b0, t2v_wk, t2v_bk,
      F9 + (size_t)F9OFF[6] * 9);

  // ---- 2. initial projections (into Hb = layer-0 input) ----
  ProjG pg;
  pg.A[0] = x_bill; pg.Kin[0] = 770; pg.Kp[0] = 800; pg.Wt[0] = WT_pb;
  pg.bias[0] = pb_b; pg.C[0] = Hb + (size_t)OFFS[0] * 128; pg.M[0] = cNB;
  pg.A[1] = x_bv; pg.Kin[1] = 390; pg.Kp[1] = 416; pg.Wt[1] = WT_pbv;
  pg.bias[1] = pbv_b; pg.C[1] = Hb + (size_t)OFFS[1] * 128; pg.M[1] = cNBV;
  pg.blkStart[0] = 0; pg.blkStart[1] = cdiv(cNB, 64);
  pg.blkStart[2] = pg.blkStart[1] + cdiv(cNBV, 64);
  gemm_proj<<<pg.blkStart[2], 256, 0, stream>>>(pg);
  proj_lt_kernel<<<cNLT, 128, 0, stream>>>(x_lt, plt_W1, plt_b1, plt_W2, plt_b2,
                                           Hb + (size_t)OFFS[2] * 128, cNLT);
  proj_comm_kernel<<<cNC, 128, 0, stream>>>(x_comm, pc_W1, pc_b1, pc_W2, pc_b2,
                                            Hb + (size_t)OFFS[3] * 128, cNC);

  // ---- 3. SAGE layers (ping-pong: Hb -> Hh2 -> Hb -> Hh2) ----
  const int KTt[5]   = {512, 384, 256, 256, 256};
  const int TOFFt[5] = {0, 512 * 128, 896 * 128, 1152 * 128, 1408 * 128};
  const int SEGOFF[5][3] = {{0, 260000, 312115}, {50000, 150000, -1},
                            {250000, -1, -1}, {310000, -1, -1}, {312000, -1, -1}};
  ushort* HP[2] = {Hb, Hh2};

  for (int l = 0; l < cLAYERS; ++l) {
    ushort* HCUR = HP[l & 1];
    ushort* HNXT = HP[(l + 1) & 1];

    hipMemsetAsync(SPtop, 0, (size_t)cNT * 128 * sizeof(float), stream);

    GatherAll ga;
    for (int r = 0; r < 8; ++r) ga.Hsrc[r] = HCUR + (size_t)OFFS[SRCT[r]] * 128;
    ga.eW = edge_W; ga.eb = edge_b; ga.col = col; ga.rp = rp; ga.F9 = F9;
    ga.S = Sall; ga.SPtop = SPtop;
    for (int r = 0; r < 7; ++r) ga.f9off[r] = F9OFF[r];
    gather_all<<<cdiv(QW_TOTAL * 16, 256), 256, 0, stream>>>(ga);
    finalize_split<<<cdiv(cNT * 64, 256), 256, 0, stream>>>(
        SPtop, rp + F9OFF[6], F9 + (size_t)F9OFF[6] * 9,
        edge_W + (size_t)6 * 9 * 128, edge_b + (size_t)6 * 128,
        Sall + (size_t)F9OFF[6] * 128, cNT);

    SageG sg;
    sg.blkStart[0] = 0;
    for (int t = 0; t < 5; ++t) {
      sg.M[t] = NSZ[t]; sg.Ktot[t] = KTt[t];
      sg.C[t] = HNXT + (size_t)OFFS[t] * 128;             // ping-pong target
      sg.A[t][0] = HCUR + (size_t)OFFS[t] * 128;
      for (int q = 0; q < 3; ++q)
        sg.A[t][q + 1] = (SEGOFF[t][q] >= 0) ? Sall + (size_t)SEGOFF[t][q] * 128 : nullptr;
      sg.Wt[t] = WC + (size_t)l * (1664 * 128) + TOFFt[t];
      sg.bias[t] = BC + (size_t)(l * 5 + t) * 128;
      sg.lng[t] = ln_g + (size_t)(l * 5 + t) * 128;
      sg.lnb[t] = ln_b + (size_t)(l * 5 + t) * 128;
      sg.blkStart[t + 1] = sg.blkStart[t] + cdiv(NSZ[t], 64);
    }
    gemm_sage<<<sg.blkStart[5], 256, 0, stream>>>(sg);
  }
  ushort* HF = HP[cLAYERS & 1];   // final H (= Hh2 for 3 layers)

  // ---- 4. head ----
  gather_bill<<<cdiv(cNB * 16, 256), 256, 0, stream>>>(
      HF + (size_t)OFFS[1] * 128, col, rp, HF + (size_t)OFFS[0] * 128, hbill_b, cNB);
  gemm_abf<1, false><<<dim3(2, cdiv(cNB, 128)), 256, 0, stream>>>(
      hbill_b, hbill_b, hbill_b, hbill_b, 128, WT_kv, 128, BKV, KVb, 256, cNB);
  gemm_abf<1, false><<<dim3(1, cdiv(cNLT, 128)), 256, 0, stream>>>(
      HF + (size_t)OFFS[2] * 128, nullptr, nullptr, nullptr, 128, WT_q, 128,
      xq_b, Ql, 128, cNLT);
  attn_lite<<<cdiv(cNVOTE * 64, 256), 256, 0, stream>>>(
      Ql, KVb, vote_lt, vote_bv, ei_isv + cNBV, t_for_bill, CT, tpv, cNVOTE);

  const int VCH = 50000;
  for (int v0 = 0; v0 < cNVOTE; v0 += VCH) {
    const int nv = (cNVOTE - v0 < VCH) ? (cNVOTE - v0) : VCH;
    gemm_gat4<true><<<dim3(2, cdiv(nv, 128)), 256, 0, stream>>>(
        HF + (size_t)OFFS[2] * 128, vote_lt + v0,
        HF + (size_t)OFFS[1] * 128, vote_bv + v0,
        HF + (size_t)OFFS[4] * 128, tpv + v0,
        CT + (size_t)v0 * 128,
        WH, BH, Uc, 256, nv);
    gemm_abf<2, false><<<dim3(1, cdiv(nv, 128)), 256, 0, stream>>>(
        Uc, Uc + 128, nullptr, nullptr, 256, WT_v2, 256, v_b2, Gc, 128, nv);
    final_out<<<cdiv(nv, 4), 256, 0, stream>>>(Gc, v_Wo, v_bo, out, v0, nv);
  }
}

// Round 19
// 1218.589 us; speedup vs baseline: 1.1967x; 1.0348x over previous
//
#include <hip/hip_runtime.h>
#include <math.h>

// ---------------- problem constants ----------------
constexpr int cNB = 50000, cNBV = 100000, cNLT = 10000, cNC = 2000, cNT = 115;
constexpr int cEV = 400000, cER = 50000, cNVOTE = 100000;
constexpr int cNTOT = cNB + cNBV + cNLT + cNC + cNT;   // 162115
constexpr int cLAYERS = 3;
constexpr int F9TOT = 362115;   // sum of n_dst over 8 relations
constexpr int ETOT  = 1200000;  // sum of E over 8 relations
constexpr int LS = 40;          // LDS row stride in shorts (80B = 5*16B)

typedef __attribute__((ext_vector_type(8))) short bf16x8;
typedef __attribute__((ext_vector_type(4))) float f32x4;
union pack8 { uint4 u; bf16x8 v; };

__device__ __forceinline__ ushort f2b(float f) {
  union { float f; uint u; } v; v.f = f;
  uint r = v.u + 0x7fffu + ((v.u >> 16) & 1u);   // RNE
  return (ushort)(r >> 16);
}
__device__ __forceinline__ float b2f(ushort b) {
  union { uint u; float f; } v; v.u = ((uint)b) << 16; return v.f;
}

// ====== fused SAGE GEMM + LayerNorm epilogue: 64-row tile, wave = 16x128 strip ======
// Reads H_cur (A0) + Sall segments, writes LN(new) to H_next (ping-pong, NOT in place).
struct SageG {
  const ushort* A[5][4];
  const ushort* Wt[5];
  const float* bias[5];
  const float* lng[5];
  const float* lnb[5];
  ushort* C[5];
  int M[5];
  int Ktot[5];
  int blkStart[6];
};

__global__ __launch_bounds__(256)
void gemm_sage(SageG sg)
{
  __shared__ ushort As[64 * LS];
  __shared__ ushort Bs[128 * LS];
  const int bid = blockIdx.x;
  int t = 0;
  while (bid >= sg.blkStart[t + 1]) ++t;
  const int row0 = (bid - sg.blkStart[t]) << 6;
  const int M = sg.M[t], Ktot = sg.Ktot[t];
  const ushort* Wt = sg.Wt[t];
  const int tid = threadIdx.x;
  const int l = tid & 63, wid = tid >> 6;
  const int lr = l & 15, lkh = l >> 4;
  const int arow = tid >> 2, aq = tid & 3;   // staging: 64 rows x 4 quarters

  f32x4 acc[8];
#pragma unroll
  for (int n = 0; n < 8; ++n) acc[n] = (f32x4)0.f;

  uint4 pa, pb0, pb1;
  auto loadAB = [&](int kk) {
    const ushort* Ap = sg.A[t][kk >> 7];
    const int k0 = kk & 127;
    const int gr = row0 + arow;
    pa = make_uint4(0, 0, 0, 0);
    if (gr < M) pa = *(const uint4*)(Ap + (size_t)gr * 128 + k0 + aq * 8);
    pb0 = *(const uint4*)(Wt + (size_t)arow * Ktot + kk + aq * 8);
    pb1 = *(const uint4*)(Wt + (size_t)(arow + 64) * Ktot + kk + aq * 8);
  };

  loadAB(0);
  for (int kk = 0; kk < Ktot; kk += 32) {
    *(uint4*)&As[arow * LS + aq * 8] = pa;
    *(uint4*)&Bs[arow * LS + aq * 8] = pb0;
    *(uint4*)&Bs[(arow + 64) * LS + aq * 8] = pb1;
    __syncthreads();
    if (kk + 32 < Ktot) loadAB(kk + 32);
    const bf16x8 af = *(const bf16x8*)&As[(wid * 16 + lr) * LS + lkh * 8];
    bf16x8 bf[8];
#pragma unroll
    for (int n = 0; n < 8; ++n)
      bf[n] = *(const bf16x8*)&Bs[(n * 16 + lr) * LS + lkh * 8];
#pragma unroll
    for (int n = 0; n < 8; ++n)
      acc[n] = __builtin_amdgcn_mfma_f32_16x16x32_bf16(af, bf[n], acc[n], 0, 0, 0);
    __syncthreads();
  }

  const float* bias = sg.bias[t];
  const float* g = sg.lng[t];
  const float* bb = sg.lnb[t];
  ushort* C = sg.C[t];
  const int rbase = row0 + wid * 16 + lkh * 4;
  float bi[8], gv[8], bv[8];
#pragma unroll
  for (int n = 0; n < 8; ++n) {
    const int col = n * 16 + lr;
    bi[n] = bias[col]; gv[n] = g[col]; bv[n] = bb[col];
  }
#pragma unroll
  for (int j = 0; j < 4; ++j) {
    const int gr = rbase + j;
    float x[8];
    float s = 0.f;
#pragma unroll
    for (int n = 0; n < 8; ++n) { x[n] = acc[n][j] + bi[n]; s += x[n]; }
#pragma unroll
    for (int m = 1; m < 16; m <<= 1) s += __shfl_xor(s, m);
    const float mean = s * (1.f / 128.f);
    float v = 0.f;
#pragma unroll
    for (int n = 0; n < 8; ++n) { const float d = x[n] - mean; v += d * d; }
#pragma unroll
    for (int m = 1; m < 16; m <<= 1) v += __shfl_xor(v, m);
    const float rinv = rsqrtf(v * (1.f / 128.f) + 1e-5f);
    if (gr < M) {
#pragma unroll
      for (int n = 0; n < 8; ++n) {
        const int col = n * 16 + lr;
        C[(size_t)gr * 128 + col] = f2b((x[n] - mean) * rinv * gv[n] + bv[n]);
      }
    }
  }
}

// ============ bf16 MFMA GEMM (head): up to 4 segments, generic N, reg-prefetch ============
template<int NSEG, bool RELU>
__global__ __launch_bounds__(256)
void gemm_abf(const ushort* __restrict__ A0, const ushort* __restrict__ A1,
              const ushort* __restrict__ A2, const ushort* __restrict__ A3,
              int Astride, const ushort* __restrict__ Wt, int Ktot,
              const float* __restrict__ bias, ushort* __restrict__ C,
              int Cstride, int M)
{
  __shared__ ushort As[128 * LS];
  __shared__ ushort Bs[128 * LS];
  const int tid = threadIdx.x;
  const int row0 = blockIdx.y << 7;
  const int col0 = blockIdx.x << 7;
  const int l = tid & 63, wid = tid >> 6;
  const int wr = wid >> 1, wc = wid & 1;
  const int lr = l & 15, lkh = l >> 4;
  const int srow = tid >> 2, sq = tid & 3;

  f32x4 acc[4][4];
#pragma unroll
  for (int m = 0; m < 4; ++m)
#pragma unroll
    for (int n = 0; n < 4; ++n) acc[m][n] = (f32x4)0.f;

  const int KT2 = NSEG * 128;
  uint4 pa0, pa1, pb0, pb1;
  auto loadAB = [&](int kk) {
    const int ks = kk >> 7;
    const ushort* Ap = (ks == 0) ? A0 : (ks == 1) ? A1 : (ks == 2) ? A2 : A3;
    const int k0 = kk & 127;
    {
      const int gr = row0 + srow;
      pa0 = make_uint4(0, 0, 0, 0);
      if (gr < M) pa0 = *(const uint4*)(Ap + (size_t)gr * Astride + k0 + sq * 8);
      pb0 = *(const uint4*)(Wt + (size_t)(col0 + srow) * Ktot + kk + sq * 8);
    }
    {
      const int gr = row0 + srow + 64;
      pa1 = make_uint4(0, 0, 0, 0);
      if (gr < M) pa1 = *(const uint4*)(Ap + (size_t)gr * Astride + k0 + sq * 8);
      pb1 = *(const uint4*)(Wt + (size_t)(col0 + srow + 64) * Ktot + kk + sq * 8);
    }
  };

  loadAB(0);
  for (int kk = 0; kk < KT2; kk += 32) {
    *(uint4*)&As[srow * LS + sq * 8] = pa0;
    *(uint4*)&As[(srow + 64) * LS + sq * 8] = pa1;
    *(uint4*)&Bs[srow * LS + sq * 8] = pb0;
    *(uint4*)&Bs[(srow + 64) * LS + sq * 8] = pb1;
    __syncthreads();
    if (kk + 32 < KT2) loadAB(kk + 32);
    bf16x8 af[4], bf[4];
#pragma unroll
    for (int m = 0; m < 4; ++m)
      af[m] = *(const bf16x8*)&As[(wr * 64 + m * 16 + lr) * LS + lkh * 8];
#pragma unroll
    for (int n = 0; n < 4; ++n)
      bf[n] = *(const bf16x8*)&Bs[(wc * 64 + n * 16 + lr) * LS + lkh * 8];
#pragma unroll
    for (int m = 0; m < 4; ++m)
#pragma unroll
      for (int n = 0; n < 4; ++n)
        acc[m][n] = __builtin_amdgcn_mfma_f32_16x16x32_bf16(af[m], bf[n], acc[m][n], 0, 0, 0);
    __syncthreads();
  }

#pragma unroll
  for (int n = 0; n < 4; ++n) {
    const int col = col0 + wc * 64 + n * 16 + lr;
    const float bi = bias[col];
#pragma unroll
    for (int m = 0; m < 4; ++m) {
      const f32x4 v = acc[m][n];
      const int rbase = row0 + wr * 64 + m * 16 + lkh * 4;
#pragma unroll
      for (int j = 0; j < 4; ++j) {
        const int gr = rbase + j;
        if (gr < M) {
          float x = v[j] + bi;
          if (RELU) x = fmaxf(x, 0.f);
          C[(size_t)gr * Cstride + col] = f2b(x);
        }
      }
    }
  }
}

// ============ gather-GEMM: 4 segments with per-row index arrays, reg-prefetch ============
template<bool RELU>
__global__ __launch_bounds__(256)
void gemm_gat4(const ushort* __restrict__ A0, const int* __restrict__ i0,
               const ushort* __restrict__ A1, const int* __restrict__ i1,
               const ushort* __restrict__ A2, const int* __restrict__ i2,
               const ushort* __restrict__ A3,
               const ushort* __restrict__ Wt, const float* __restrict__ bias,
               ushort* __restrict__ C, int Cstride, int M)
{
  __shared__ ushort As[128 * LS];
  __shared__ ushort Bs[128 * LS];
  const int tid = threadIdx.x;
  const int row0 = blockIdx.y << 7;
  const int col0 = blockIdx.x << 7;
  const int l = tid & 63, wid = tid >> 6;
  const int wr = wid >> 1, wc = wid & 1;
  const int lr = l & 15, lkh = l >> 4;
  const int srow = tid >> 2, sq = tid & 3;

  f32x4 acc[4][4];
#pragma unroll
  for (int m = 0; m < 4; ++m)
#pragma unroll
    for (int n = 0; n < 4; ++n) acc[m][n] = (f32x4)0.f;

  uint4 pa0, pa1, pb0, pb1;
  auto loadAB = [&](int kk) {
    const int ks = kk >> 7;
    const ushort* Ap = (ks == 0) ? A0 : (ks == 1) ? A1 : (ks == 2) ? A2 : A3;
    const int* ip = (ks == 0) ? i0 : (ks == 1) ? i1 : (ks == 2) ? i2 : nullptr;
    const int k0 = kk & 127;
    {
      const int gr = row0 + srow;
      pa0 = make_uint4(0, 0, 0, 0);
      if (gr < M) {
        const int ar = ip ? ip[gr] : gr;
        pa0 = *(const uint4*)(Ap + (size_t)ar * 128 + k0 + sq * 8);
      }
      pb0 = *(const uint4*)(Wt + (size_t)(col0 + srow) * 512 + kk + sq * 8);
    }
    {
      const int gr = row0 + srow + 64;
      pa1 = make_uint4(0, 0, 0, 0);
      if (gr < M) {
        const int ar = ip ? ip[gr] : gr;
        pa1 = *(const uint4*)(Ap + (size_t)ar * 128 + k0 + sq * 8);
      }
      pb1 = *(const uint4*)(Wt + (size_t)(col0 + srow + 64) * 512 + kk + sq * 8);
    }
  };

  loadAB(0);
  for (int kk = 0; kk < 512; kk += 32) {
    *(uint4*)&As[srow * LS + sq * 8] = pa0;
    *(uint4*)&As[(srow + 64) * LS + sq * 8] = pa1;
    *(uint4*)&Bs[srow * LS + sq * 8] = pb0;
    *(uint4*)&Bs[(srow + 64) * LS + sq * 8] = pb1;
    __syncthreads();
    if (kk + 32 < 512) loadAB(kk + 32);
    bf16x8 af[4], bf[4];
#pragma unroll
    for (int m = 0; m < 4; ++m)
      af[m] = *(const bf16x8*)&As[(wr * 64 + m * 16 + lr) * LS + lkh * 8];
#pragma unroll
    for (int n = 0; n < 4; ++n)
      bf[n] = *(const bf16x8*)&Bs[(wc * 64 + n * 16 + lr) * LS + lkh * 8];
#pragma unroll
    for (int m = 0; m < 4; ++m)
#pragma unroll
      for (int n = 0; n < 4; ++n)
        acc[m][n] = __builtin_amdgcn_mfma_f32_16x16x32_bf16(af[m], bf[n], acc[m][n], 0, 0, 0);
    __syncthreads();
  }

#pragma unroll
  for (int n = 0; n < 4; ++n) {
    const int col = col0 + wc * 64 + n * 16 + lr;
    const float bi = bias[col];
#pragma unroll
    for (int m = 0; m < 4; ++m) {
      const f32x4 v = acc[m][n];
      const int rbase = row0 + wr * 64 + m * 16 + lkh * 4;
#pragma unroll
      for (int j = 0; j < 4; ++j) {
        const int gr = rbase + j;
        if (gr < M) {
          float x = v[j] + bi;
          if (RELU) x = fmaxf(x, 0.f);
          C[(size_t)gr * Cstride + col] = f2b(x);
        }
      }
    }
  }
}

// ====== fused fp32-A projection GEMMs: 64-row tile, wave = 16x128 strip ======
struct ProjG {
  const float* A[2];
  int Kin[2], Kp[2];
  const ushort* Wt[2];
  const float* bias[2];
  ushort* C[2];
  int M[2];
  int blkStart[3];
};

__global__ __launch_bounds__(256)
void gemm_proj(ProjG pg)
{
  __shared__ ushort As[64 * LS];
  __shared__ ushort Bs[128 * LS];
  const int bid = blockIdx.x;
  const int t = (bid >= pg.blkStart[1]) ? 1 : 0;
  const int row0 = (bid - pg.blkStart[t]) << 6;
  const float* A = pg.A[t];
  const ushort* Wt = pg.Wt[t];
  const int Kin = pg.Kin[t], Kp = pg.Kp[t], M = pg.M[t];
  const int tid = threadIdx.x;
  const int l = tid & 63, wid = tid >> 6;
  const int lr = l & 15, lkh = l >> 4;
  const int arow = tid >> 2, aq = tid & 3;

  f32x4 acc[8];
#pragma unroll
  for (int n = 0; n < 8; ++n) acc[n] = (f32x4)0.f;

  float4 pfa0, pfa1;
  uint4 pw0, pw1;
  auto loadP = [&](int kk) {
    const int gk = kk + aq * 8;
    const int gr = row0 + arow;
    float4 f0 = make_float4(0.f, 0.f, 0.f, 0.f), f1 = f0;
    if (gr < M) {
      const float* ap = A + (size_t)gr * Kin + gk;
      if (gk + 7 < Kin) { f0 = *(const float4*)ap; f1 = *(const float4*)(ap + 4); }
      else {
        float tv[8];
#pragma unroll
        for (int j = 0; j < 8; ++j) tv[j] = (gk + j < Kin) ? ap[j] : 0.f;
        f0 = make_float4(tv[0], tv[1], tv[2], tv[3]);
        f1 = make_float4(tv[4], tv[5], tv[6], tv[7]);
      }
    }
    pfa0 = f0; pfa1 = f1;
    pw0 = *(const uint4*)(Wt + (size_t)arow * Kp + kk + aq * 8);
    pw1 = *(const uint4*)(Wt + (size_t)(arow + 64) * Kp + kk + aq * 8);
  };

  loadP(0);
  for (int kk = 0; kk < Kp; kk += 32) {
    {
      uint4 w;
      w.x = f2b(pfa0.x) | ((uint)f2b(pfa0.y) << 16);
      w.y = f2b(pfa0.z) | ((uint)f2b(pfa0.w) << 16);
      w.z = f2b(pfa1.x) | ((uint)f2b(pfa1.y) << 16);
      w.w = f2b(pfa1.z) | ((uint)f2b(pfa1.w) << 16);
      *(uint4*)&As[arow * LS + aq * 8] = w;
      *(uint4*)&Bs[arow * LS + aq * 8] = pw0;
      *(uint4*)&Bs[(arow + 64) * LS + aq * 8] = pw1;
    }
    __syncthreads();
    if (kk + 32 < Kp) loadP(kk + 32);
    const bf16x8 af = *(const bf16x8*)&As[(wid * 16 + lr) * LS + lkh * 8];
    bf16x8 bf[8];
#pragma unroll
    for (int n = 0; n < 8; ++n)
      bf[n] = *(const bf16x8*)&Bs[(n * 16 + lr) * LS + lkh * 8];
#pragma unroll
    for (int n = 0; n < 8; ++n)
      acc[n] = __builtin_amdgcn_mfma_f32_16x16x32_bf16(af, bf[n], acc[n], 0, 0, 0);
    __syncthreads();
  }

  const float* bias = pg.bias[t];
  ushort* C = pg.C[t];
  const int rbase = row0 + wid * 16 + lkh * 4;
#pragma unroll
  for (int n = 0; n < 8; ++n) {
    const int col = n * 16 + lr;
    const float bi = bias[col];
    const f32x4 v = acc[n];
#pragma unroll
    for (int j = 0; j < 4; ++j) {
      const int gr = rbase + j;
      if (gr < M) C[(size_t)gr * 128 + col] = f2b(v[j] + bi);
    }
  }
}

// ================= weight conversion =================
__global__ void conv_wt(const float* __restrict__ W, ushort* __restrict__ Wt,
                        int K, int N, int Kp)
{
  const int kp = blockIdx.x * 256 + threadIdx.x;
  const int n = blockIdx.y;
  if (kp >= Kp) return;
  const float v = (kp < K) ? W[(size_t)kp * N + n] : 0.f;
  Wt[(size_t)n * Kp + kp] = f2b(v);
}

__global__ void conv_wcat(const float* __restrict__ Wl, const float* __restrict__ bl,
                          const float* __restrict__ Wr, const float* __restrict__ br,
                          ushort* __restrict__ WC, float* __restrict__ BC)
{
  const int KT[5]   = {512, 384, 256, 256, 256};
  const int TOFF[5] = {0, 512 * 128, 896 * 128, 1152 * 128, 1408 * 128};
  const int RL[5][3] = {{0, 4, 7}, {1, 2, -1}, {3, -1, -1}, {5, -1, -1}, {6, -1, -1}};
  const int NS[5] = {3, 2, 1, 1, 1};
  const int lt = blockIdx.y;
  const int lay = lt / 5, tt = lt % 5;
  const int idx = blockIdx.x * 256 + threadIdx.x;
  const int kk = idx >> 7, n = idx & 127;
  const int Kt = KT[tt];
  ushort* w = WC + (size_t)lay * (1664 * 128) + TOFF[tt] + (size_t)n * Kt;
  float s = 0.f;
  for (int q = 0; q < NS[tt]; ++q) {
    const int r = RL[tt][q];
    s += Wr[((size_t)lay * 8 + r) * 16384 + kk * 128 + n];
    w[(q + 1) * 128 + kk] = f2b(Wl[((size_t)lay * 8 + r) * 16384 + kk * 128 + n]);
  }
  w[kk] = f2b(s);
  if (kk == 0) {
    float b = 0.f;
    for (int q = 0; q < NS[tt]; ++q) {
      const int r = RL[tt][q];
      b += bl[(lay * 8 + r) * 128 + n] + br[(lay * 8 + r) * 128 + n];
    }
    BC[lt * 128 + n] = b;
  }
}

// head weight fold: WH[256][512]; seg0..2 = v_W1^T, seg3 = (xo_W @ v_W1[384:])^T
__global__ void conv_head(const float* __restrict__ vW1, const float* __restrict__ vb1,
                          const float* __restrict__ xoW, const float* __restrict__ xob,
                          ushort* __restrict__ WH, float* __restrict__ BH)
{
  const int idx = blockIdx.x * 256 + threadIdx.x;   // 256*512
  const int n = idx >> 9, k = idx & 511;
  if (k < 384) {
    WH[(size_t)n * 512 + k] = f2b(vW1[(size_t)k * 256 + n]);
  } else {
    const int c = k - 384;
    float s = 0.f;
    for (int d = 0; d < 128; ++d)
      s += xoW[c * 128 + d] * vW1[(size_t)(384 + d) * 256 + n];
    WH[(size_t)n * 512 + k] = f2b(s);
    if (c == 0) {
      float bb = vb1[n];
      for (int d = 0; d < 128; ++d)
        bb += xob[d] * vW1[(size_t)(384 + d) * 256 + n];
      BH[n] = bb;
    }
  }
}

__global__ void concat_bias2(const float* __restrict__ a, const float* __restrict__ b,
                             float* __restrict__ o)
{
  const int i = threadIdx.x;
  o[i] = (i < 128) ? a[i] : b[i - 128];
}

__global__ void conv_f2b_kernel(const float* __restrict__ in, ushort* __restrict__ out, int n)
{
  const int i = blockIdx.x * 256 + threadIdx.x;
  if (i < n) out[i] = f2b(in[i]);
}

// ================= small projection MLPs (bf16 out) =================
__global__ void proj_lt_kernel(const float* __restrict__ X, const float* __restrict__ W1,
                               const float* __restrict__ b1, const float* __restrict__ W2,
                               const float* __restrict__ b2, ushort* __restrict__ Y, int n)
{
  __shared__ float xs[4];
  __shared__ float hid[64];
  const int node = blockIdx.x, tid = threadIdx.x;
  if (node >= n) return;
  if (tid < 4) xs[tid] = X[(size_t)node * 4 + tid];
  __syncthreads();
  if (tid < 64) {
    float a = b1[tid];
#pragma unroll
    for (int k = 0; k < 4; ++k) a += xs[k] * W1[k * 64 + tid];
    hid[tid] = fmaxf(a, 0.f);
  }
  __syncthreads();
  float o = b2[tid];
  for (int k = 0; k < 64; ++k) o += hid[k] * W2[k * 128 + tid];
  Y[(size_t)node * 128 + tid] = f2b(o);
}

__global__ void proj_comm_kernel(const float* __restrict__ X, const float* __restrict__ W1,
                                 const float* __restrict__ b1, const float* __restrict__ W2,
                                 const float* __restrict__ b2, ushort* __restrict__ Y, int n)
{
  __shared__ float xs[65];
  __shared__ float hid[128];
  const int node = blockIdx.x, tid = threadIdx.x;
  if (node >= n) return;
  if (tid < 65) xs[tid] = X[(size_t)node * 65 + tid];
  __syncthreads();
  float a = b1[tid];
  for (int k = 0; k < 65; ++k) a += xs[k] * W1[k * 128 + tid];
  hid[tid] = fmaxf(a, 0.f);
  __syncthreads();
  float o = b2[tid];
  for (int k = 0; k < 128; ++k) o += hid[k] * W2[k * 128 + tid];
  Y[(size_t)node * 128 + tid] = f2b(o);
}

// ================= fused CSR build =================
struct EdgesAll {
  const int* src[8];
  const int* dst[8];
  int estart[9];
  int f9off[8];
};

__global__ void hist_all(EdgesAll ea, int* __restrict__ deg)
{
  const int e = blockIdx.x * 256 + threadIdx.x;
  if (e >= ea.estart[8]) return;
  int r = 0;
  while (e >= ea.estart[r + 1]) ++r;
  const int el = e - ea.estart[r];
  atomicAdd(&deg[ea.f9off[r] + ea.dst[r][el]], 1);
}

__global__ void fill_all(EdgesAll ea, const int* __restrict__ rp,
                         int* __restrict__ cur, int2* __restrict__ col)
{
  const int e = blockIdx.x * 256 + threadIdx.x;
  if (e >= ea.estart[8]) return;
  int r = 0;
  while (e >= ea.estart[r + 1]) ++r;
  const int el = e - ea.estart[r];
  const int d = ea.f9off[r] + ea.dst[r][el];
  const int p = atomicAdd(&cur[d], 1);
  col[rp[d] + p] = make_int2(ea.src[r][el], el);
}

__global__ __launch_bounds__(256)
void scan_blk(const int* __restrict__ in, int* __restrict__ out,
              int* __restrict__ bsum, int n)
{
  __shared__ int wsum[4];
  const int t = threadIdx.x;
  const int base = blockIdx.x * 1024 + t * 4;
  const int v0 = (base + 0 < n) ? in[base + 0] : 0;
  const int v1 = (base + 1 < n) ? in[base + 1] : 0;
  const int v2 = (base + 2 < n) ? in[base + 2] : 0;
  const int v3 = (base + 3 < n) ? in[base + 3] : 0;
  const int s = v0 + v1 + v2 + v3;
  const int lane = t & 63;
  int incl = s;
#pragma unroll
  for (int m = 1; m < 64; m <<= 1) {
    const int o = __shfl_up(incl, m);
    if (lane >= m) incl += o;
  }
  const int wid = t >> 6;
  if (lane == 63) wsum[wid] = incl;
  __syncthreads();
  int woff = 0;
#pragma unroll
  for (int w = 0; w < 3; ++w) woff += (w < wid) ? wsum[w] : 0;
  int run = woff + incl - s;
  if (base + 0 < n) out[base + 0] = run; run += v0;
  if (base + 1 < n) out[base + 1] = run; run += v1;
  if (base + 2 < n) out[base + 2] = run; run += v2;
  if (base + 3 < n) out[base + 3] = run;
  if (bsum != nullptr && t == 255) bsum[blockIdx.x] = woff + incl;
}

__global__ void scan_add(int* __restrict__ rp, const int* __restrict__ bsum, int n)
{
  const int i = blockIdx.x * 1024 + threadIdx.x * 4;
  const int add = bsum[blockIdx.x];
#pragma unroll
  for (int k = 0; k < 4; ++k)
    if (i + k < n) rp[i + k] += add;
}

// ======== F9: ONE THREAD per node (deg is tiny); r6 handled by f9_topic ========
struct F9All {
  const float* tt[8];
  int f9off[9];
};

__global__ __launch_bounds__(256)
void f9_thread(F9All fa, const int2* __restrict__ col, const int* __restrict__ rp,
               const float* __restrict__ w0p, const float* __restrict__ b0p,
               const float* __restrict__ wkp, const float* __restrict__ bkp,
               float* __restrict__ F9)
{
  const int node = blockIdx.x * 256 + threadIdx.x;
  if (node >= F9TOT) return;
  float* fo = F9 + (size_t)node * 9;
  if (node >= 312000 && node < 312115) {   // r6 range: written by f9_topic
#pragma unroll
    for (int k = 0; k < 9; ++k) fo[k] = 0.f;
    return;
  }
  int r = 0;
  while (node >= fa.f9off[r + 1]) ++r;
  const float* tvals = fa.tt[r];
  const int e0 = rp[node], e1 = rp[node + 1];
  const float w0 = w0p[0], b0 = b0p[0];
  float wk[8], bk[8];
#pragma unroll
  for (int k = 0; k < 8; ++k) { wk[k] = wkp[k]; bk[k] = bkp[k]; }
  float st = 0.f;
  float fk[8];
#pragma unroll
  for (int k = 0; k < 8; ++k) fk[k] = 0.f;
  for (int e = e0; e < e1; ++e) {
    const float tv = tvals[col[e].y];
    st += tv;
#pragma unroll
    for (int k = 0; k < 8; ++k) fk[k] += __sinf(tv * wk[k] + bk[k]);
  }
  fo[0] = st * w0 + (float)(e1 - e0) * b0;
#pragma unroll
  for (int k = 0; k < 8; ++k) fo[1 + k] = fk[k];
}

// r6 (topic, deg~435): 64 threads (= one wave) per node; deterministic
// in-wave butterfly reduction, lane 0 writes (no fp32 atomics).
__global__ void f9_topic(const int2* __restrict__ col, const int* __restrict__ rp,
                         const float* __restrict__ tvals,
                         const float* __restrict__ w0p, const float* __restrict__ b0p,
                         const float* __restrict__ wkp, const float* __restrict__ bkp,
                         float* __restrict__ F9)
{
  const int t = blockIdx.x * 256 + threadIdx.x;
  if (t >= cNT * 64) return;
  const int node = t >> 6, j = t & 63;
  const int e0 = rp[node], e1 = rp[node + 1];
  const float w0 = w0p[0], b0 = b0p[0];
  float wk[8], bk[8];
#pragma unroll
  for (int k = 0; k < 8; ++k) { wk[k] = wkp[k]; bk[k] = bkp[k]; }
  float st = 0.f;
  float fk[8];
#pragma unroll
  for (int k = 0; k < 8; ++k) fk[k] = 0.f;
  int cnt = 0;
  for (int e = e0 + j; e < e1; e += 64) {
    const float tv = tvals[col[e].y];
    st += tv; ++cnt;
#pragma unroll
    for (int k = 0; k < 8; ++k) fk[k] += __sinf(tv * wk[k] + bk[k]);
  }
  float v0 = st * w0 + (float)cnt * b0;
#pragma unroll
  for (int m = 1; m < 64; m <<= 1) {
    v0 += __shfl_xor(v0, m);
#pragma unroll
    for (int k = 0; k < 8; ++k) fk[k] += __shfl_xor(fk[k], m);
  }
  if (j == 0) {
    float* fo = F9 + (size_t)node * 9;
    fo[0] = v0;
#pragma unroll
    for (int k = 0; k < 8; ++k) fo[1 + k] = fk[k];
  }
}

// ======== fused per-layer gather: QUARTER-WAVE per node, uint4 rows ========
constexpr int QW_SPLIT0 = 312000;             // nodes before rel6 split section
constexpr int QW_SPLIT1 = 312000 + 115 * 64;  // end of split section
constexpr int QW_TOTAL  = QW_SPLIT1 + 50000;  // + rel7 nodes

struct GatherAll {
  const ushort* Hsrc[8];
  const float* eW;      // edge_W base
  const float* eb;      // edge_b base
  const int2* col;
  const int* rp;
  const float* F9;
  ushort* S;
  float* SPtop;
  int f9off[7];   // {0,50000,150000,250000,260000,310000,312000}
};

__global__ __launch_bounds__(256)
void gather_all(GatherAll ga)
{
  const int qw = (blockIdx.x * 256 + threadIdx.x) >> 4;
  if (qw >= QW_TOTAL) return;
  const int lq = threadIdx.x & 15;
  int node, r, splitj = -1;
  if (qw < QW_SPLIT0) {
    node = qw;
    r = 0;
    while (node >= ga.f9off[r + 1]) ++r;     // r in 0..5
  } else if (qw < QW_SPLIT1) {
    const int lw = qw - QW_SPLIT0;
    node = QW_SPLIT0 + (lw >> 6);
    splitj = lw & 63;
    r = 6;
  } else {
    node = 312115 + (qw - QW_SPLIT1);
    r = 7;
  }
  const int e0 = ga.rp[node], e1 = ga.rp[node + 1];
  const uint4* H4 = (const uint4*)ga.Hsrc[r];
  float a[8];
#pragma unroll
  for (int i = 0; i < 8; ++i) a[i] = 0.f;

#define ACC8(v)                                              \
  { a[0] += b2f((ushort)(v).x); a[1] += b2f((ushort)((v).x >> 16)); \
    a[2] += b2f((ushort)(v).y); a[3] += b2f((ushort)((v).y >> 16)); \
    a[4] += b2f((ushort)(v).z); a[5] += b2f((ushort)((v).z >> 16)); \
    a[6] += b2f((ushort)(v).w); a[7] += b2f((ushort)((v).w >> 16)); }

  if (splitj >= 0) {
    int e = e0 + splitj;
    for (; e + 64 < e1; e += 128) {
      const int s0 = ga.col[e].x, s1 = ga.col[e + 64].x;
      const uint4 v0 = H4[(size_t)s0 * 16 + lq];
      const uint4 v1 = H4[(size_t)s1 * 16 + lq];
      ACC8(v0); ACC8(v1);
    }
    if (e < e1) { const uint4 v = H4[(size_t)ga.col[e].x * 16 + lq]; ACC8(v); }
    float* p = &ga.SPtop[(size_t)(node - QW_SPLIT0) * 128 + lq * 8];
#pragma unroll
    for (int i = 0; i < 8; ++i) atomicAdd(p + i, a[i]);
    return;
  }
  int e = e0;
  for (; e + 3 < e1; e += 4) {
    const int s0 = ga.col[e].x, s1 = ga.col[e + 1].x;
    const int s2 = ga.col[e + 2].x, s3 = ga.col[e + 3].x;
    const uint4 v0 = H4[(size_t)s0 * 16 + lq];
    const uint4 v1 = H4[(size_t)s1 * 16 + lq];
    const uint4 v2 = H4[(size_t)s2 * 16 + lq];
    const uint4 v3 = H4[(size_t)s3 * 16 + lq];
    ACC8(v0); ACC8(v1); ACC8(v2); ACC8(v3);
  }
  if (e + 1 < e1) {
    const int s0 = ga.col[e].x, s1 = ga.col[e + 1].x;
    const uint4 v0 = H4[(size_t)s0 * 16 + lq];
    const uint4 v1 = H4[(size_t)s1 * 16 + lq];
    ACC8(v0); ACC8(v1);
    e += 2;
  }
  if (e < e1) { const uint4 v = H4[(size_t)ga.col[e].x * 16 + lq]; ACC8(v); }

  const float* eW = ga.eW + (size_t)r * 9 * 128;
  const float* eb = ga.eb + (size_t)r * 128;
  float f9[9];
#pragma unroll
  for (int k = 0; k < 9; ++k) f9[k] = ga.F9[(size_t)node * 9 + k];
  const int degn = e1 - e0;
  const int j0 = lq * 8;
#pragma unroll
  for (int k = 0; k < 9; ++k) {
#pragma unroll
    for (int i = 0; i < 8; ++i) a[i] += f9[k] * eW[k * 128 + j0 + i];
  }
  const float rinv = 1.f / fmaxf((float)degn, 1.f);
#pragma unroll
  for (int i = 0; i < 8; ++i) a[i] *= rinv;
  if (degn > 0) {
#pragma unroll
    for (int i = 0; i < 8; ++i) a[i] += eb[j0 + i];
  }
  uint4 o;
  o.x = (uint)f2b(a[0]) | ((uint)f2b(a[1]) << 16);
  o.y = (uint)f2b(a[2]) | ((uint)f2b(a[3]) << 16);
  o.z = (uint)f2b(a[4]) | ((uint)f2b(a[5]) << 16);
  o.w = (uint)f2b(a[6]) | ((uint)f2b(a[7]) << 16);
  ((uint4*)ga.S)[(size_t)node * 16 + lq] = o;
#undef ACC8
}

__global__ void finalize_split(const float* __restrict__ SP, const int* __restrict__ rp,
                               const float* __restrict__ F9, const float* __restrict__ eW,
                               const float* __restrict__ eb, ushort* __restrict__ S, int nd)
{
  const int gw = (blockIdx.x * blockDim.x + threadIdx.x) >> 6;
  if (gw >= nd) return;
  const int lane = threadIdx.x & 63;
  const int degn = rp[gw + 1] - rp[gw];
  const int j = lane * 2;
  const float2 sv = *(const float2*)&SP[(size_t)gw * 128 + j];
  float f9[9];
#pragma unroll
  for (int k = 0; k < 9; ++k) f9[k] = F9[(size_t)gw * 9 + k];
  float o0 = sv.x, o1 = sv.y;
#pragma unroll
  for (int k = 0; k < 9; ++k) {
    o0 += f9[k] * eW[k * 128 + j];
    o1 += f9[k] * eW[k * 128 + j + 1];
  }
  const float rinv = 1.f / fmaxf((float)degn, 1.f);
  o0 *= rinv; o1 *= rinv;
  if (degn > 0) { o0 += eb[j]; o1 += eb[j + 1]; }
  ((uint*)S)[(size_t)gw * 64 + lane] = (uint)f2b(o0) | ((uint)f2b(o1) << 16);
}

// ======== h_bill: quarter-wave per node, uint4 rows ========
__global__ __launch_bounds__(256)
void gather_bill(const ushort* __restrict__ H1, const int2* __restrict__ col,
                 const int* __restrict__ rp, const ushort* __restrict__ H0,
                 ushort* __restrict__ S, int nB)
{
  const int qw = (blockIdx.x * 256 + threadIdx.x) >> 4;
  if (qw >= nB) return;
  const int lq = threadIdx.x & 15;
  const int e0 = rp[qw], e1 = rp[qw + 1];
  const uint4* H14 = (const uint4*)H1;
  float a[8];
#pragma unroll
  for (int i = 0; i < 8; ++i) a[i] = 0.f;
#define ACC8(v)                                              \
  { a[0] += b2f((ushort)(v).x); a[1] += b2f((ushort)((v).x >> 16)); \
    a[2] += b2f((ushort)(v).y); a[3] += b2f((ushort)((v).y >> 16)); \
    a[4] += b2f((ushort)(v).z); a[5] += b2f((ushort)((v).z >> 16)); \
    a[6] += b2f((ushort)(v).w); a[7] += b2f((ushort)((v).w >> 16)); }
  int e = e0;
  for (; e + 1 < e1; e += 2) {
    const int s0 = col[e].x, s1 = col[e + 1].x;
    const uint4 v0 = H14[(size_t)s0 * 16 + lq];
    const uint4 v1 = H14[(size_t)s1 * 16 + lq];
    ACC8(v0); ACC8(v1);
  }
  if (e < e1) { const uint4 v = H14[(size_t)col[e].x * 16 + lq]; ACC8(v); }
#undef ACC8
  const float rc = 1.f / ((float)(e1 - e0) + 1e-6f);
  const uint4 h0 = ((const uint4*)H0)[(size_t)qw * 16 + lq];
  uint4 o;
  o.x = (uint)f2b(0.5f * b2f((ushort)h0.x) + 0.5f * a[0] * rc)
      | ((uint)f2b(0.5f * b2f((ushort)(h0.x >> 16)) + 0.5f * a[1] * rc) << 16);
  o.y = (uint)f2b(0.5f * b2f((ushort)h0.y) + 0.5f * a[2] * rc)
      | ((uint)f2b(0.5f * b2f((ushort)(h0.y >> 16)) + 0.5f * a[3] * rc) << 16);
  o.z = (uint)f2b(0.5f * b2f((ushort)h0.z) + 0.5f * a[4] * rc)
      | ((uint)f2b(0.5f * b2f((ushort)(h0.z >> 16)) + 0.5f * a[5] * rc) << 16);
  o.w = (uint)f2b(0.5f * b2f((ushort)h0.w) + 0.5f * a[6] * rc)
      | ((uint)f2b(0.5f * b2f((ushort)(h0.w >> 16)) + 0.5f * a[7] * rc) << 16);
  ((uint4*)S)[(size_t)qw * 16 + lq] = o;
}

// ================= per-vote softmax attention (1 wave/vote) =================
__global__ __launch_bounds__(256)
void attn_lite(const ushort* __restrict__ Ql, const ushort* __restrict__ KVb,
               const int* __restrict__ vote_lt, const int* __restrict__ vote_bv,
               const int* __restrict__ isv_dst, const int* __restrict__ t_for_bill,
               ushort* __restrict__ CT, int* __restrict__ tpv, int nV)
{
  const int gw = (blockIdx.x * blockDim.x + threadIdx.x) >> 6;
  if (gw >= nV) return;
  const int lane = threadIdx.x & 63;
  const int bv = vote_bv[gw];
  const int lt = vote_lt[gw];
  const int b = isv_dst[bv];
  if (lane == 0) tpv[gw] = t_for_bill[b];
  const uint q  = ((const uint*)Ql)[(size_t)lt * 64 + lane];
  const uint kk = ((const uint*)KVb)[(size_t)b * 128 + lane];
  const uint vv = ((const uint*)KVb)[(size_t)b * 128 + 64 + lane];
  const float q0 = b2f((ushort)q),  q1 = b2f((ushort)(q >> 16));
  const float k0 = b2f((ushort)kk), k1 = b2f((ushort)(kk >> 16));
  float s = q0 * k0 + q1 * k1;
#pragma unroll
  for (int m = 1; m < 16; m <<= 1) s += __shfl_xor(s, m);   // 16-lane head groups
  s *= 0.17677669529663687f;                                // 1/sqrt(32)
  float mx = fmaxf(s, __shfl_xor(s, 16));
  mx = fmaxf(mx, __shfl_xor(mx, 32));
  const float e = __expf(s - mx);
  float den = e + __shfl_xor(e, 16);
  den += __shfl_xor(den, 32);
  const float a = e / den;
  const float v0f = b2f((ushort)vv), v1f = b2f((ushort)(vv >> 16));
  ((uint*)CT)[(size_t)gw * 64 + lane] =
      (uint)f2b(a * v0f) | ((uint)f2b(a * v1f) << 16);
}

// ================= final 128 -> 3 (bf16 G) =================
__global__ void final_out(const ushort* __restrict__ G, const float* __restrict__ Wo,
                          const float* __restrict__ bo, float* __restrict__ out,
                          int v0, int nV)
{
  const int wave = (blockIdx.x * blockDim.x + threadIdx.x) >> 6;
  const int lane = threadIdx.x & 63;
  if (wave >= nV) return;
  const ushort* g = G + (size_t)wave * 128;
  const float x0 = b2f(g[lane]), x1 = b2f(g[64 + lane]);
  float s0 = x0 * Wo[lane * 3 + 0] + x1 * Wo[(64 + lane) * 3 + 0];
  float s1 = x0 * Wo[lane * 3 + 1] + x1 * Wo[(64 + lane) * 3 + 1];
  float s2 = x0 * Wo[lane * 3 + 2] + x1 * Wo[(64 + lane) * 3 + 2];
#pragma unroll
  for (int m = 1; m < 64; m <<= 1) {
    s0 += __shfl_xor(s0, m);
    s1 += __shfl_xor(s1, m);
    s2 += __shfl_xor(s2, m);
  }
  if (lane == 0) {
    float* o = out + (size_t)(v0 + wave) * 3;
    o[0] = s0 + bo[0]; o[1] = s1 + bo[1]; o[2] = s2 + bo[2];
  }
}

// ================= host side =================
static inline int cdiv(int a, int b) { return (a + b - 1) / b; }

extern "C" void kernel_launch(void* const* d_in, const int* in_sizes, int n_in,
                              void* d_out, int out_size, void* d_ws, size_t ws_size,
                              hipStream_t stream)
{
  (void)in_sizes; (void)n_in; (void)out_size;

  const float* x_bill = (const float*)d_in[0];
  const float* x_bv   = (const float*)d_in[1];
  const float* x_lt   = (const float*)d_in[2];
  const float* x_comm = (const float*)d_in[3];
  const float* pb_W  = (const float*)d_in[4];
  const float* pb_b  = (const float*)d_in[5];
  const float* pbv_W = (const float*)d_in[6];
  const float* pbv_b = (const float*)d_in[7];
  const float* plt_W1 = (const float*)d_in[8];
  const float* plt_b1 = (const float*)d_in[9];
  const float* plt_W2 = (const float*)d_in[10];
  const float* plt_b2 = (const float*)d_in[11];
  const float* pc_W1 = (const float*)d_in[12];
  const float* pc_b1 = (const float*)d_in[13];
  const float* pc_W2 = (const float*)d_in[14];
  const float* pc_b2 = (const float*)d_in[15];
  const float* topic_emb = (const float*)d_in[16];
  const float* t2v_w0 = (const float*)d_in[17];
  const float* t2v_b0 = (const float*)d_in[18];
  const float* t2v_wk = (const float*)d_in[19];
  const float* t2v_bk = (const float*)d_in[20];
  const float* edge_W = (const float*)d_in[21];
  const float* edge_b = (const float*)d_in[22];
  const float* sage_Wl = (const float*)d_in[23];
  const float* sage_bl = (const float*)d_in[24];
  const float* sage_Wr = (const float*)d_in[25];
  const float* sage_br = (const float*)d_in[26];
  const float* ln_g = (const float*)d_in[27];
  const float* ln_b = (const float*)d_in[28];
  const float* xq_W = (const float*)d_in[29];
  const float* xq_b = (const float*)d_in[30];
  const float* xk_W = (const float*)d_in[31];
  const float* xk_b = (const float*)d_in[32];
  const float* xv_W = (const float*)d_in[33];
  const float* xv_b = (const float*)d_in[34];
  const float* xo_W = (const float*)d_in[35];
  const float* xo_b = (const float*)d_in[36];
  const float* v_W1 = (const float*)d_in[37];
  const float* v_b1 = (const float*)d_in[38];
  const float* v_W2 = (const float*)d_in[39];
  const float* v_b2 = (const float*)d_in[40];
  const float* v_Wo = (const float*)d_in[41];
  const float* v_bo = (const float*)d_in[42];
  const float* t_isv   = (const float*)d_in[43];
  const float* t_vote  = (const float*)d_in[44];
  const float* t_rev   = (const float*)d_in[45];
  const float* t_about = (const float*)d_in[46];
  const int* ei_isv   = (const int*)d_in[47];
  const int* ei_vote  = (const int*)d_in[48];
  const int* ei_rev   = (const int*)d_in[49];
  const int* ei_about = (const int*)d_in[50];
  const int* t_for_bill = (const int*)d_in[51];
  const int* vote_lt = (const int*)d_in[52];
  const int* vote_bv = (const int*)d_in[53];
  float* out = (float*)d_out;

  const int OFFS[5] = {0, cNB, cNB + cNBV, cNB + cNBV + cNLT, cNB + cNBV + cNLT + cNC};
  const int NSZ[5]  = {cNB, cNBV, cNLT, cNC, cNT};

  // -------- workspace layout (bytes) --------
  char* w = (char*)d_ws;
  const size_t szHb = (size_t)cNTOT * 128 * 2;            // 41.5 MB
  const size_t szS  = (size_t)F9TOT * 128 * 2;            // 92.7 MB
  ushort* Hb   = (ushort*)w;                              // ping
  ushort* Hh2  = (ushort*)(w + szHb);                     // pong
  ushort* Sall = (ushort*)(w + 2 * szHb);
  size_t off = 2 * szHb + szS;
  ushort* WT_pb  = (ushort*)(w + off); off += (size_t)128 * 800 * 2;
  ushort* WT_pbv = (ushort*)(w + off); off += (size_t)128 * 416 * 2;
  ushort* WC     = (ushort*)(w + off); off += (size_t)3 * 1664 * 128 * 2;
  ushort* WT_v2  = (ushort*)(w + off); off += (size_t)128 * 256 * 2;
  ushort* WT_q   = (ushort*)(w + off); off += (size_t)128 * 128 * 2;
  ushort* WT_kv  = (ushort*)(w + off); off += (size_t)256 * 128 * 2;
  ushort* WH     = (ushort*)(w + off); off += (size_t)256 * 512 * 2;
  off = (off + 15) & ~(size_t)15;
  float* BC  = (float*)(w + off); off += (size_t)15 * 128 * 4;
  float* BH  = (float*)(w + off); off += (size_t)256 * 4;
  float* BKV = (float*)(w + off); off += (size_t)256 * 4;
  float* SPtop = (float*)(w + off); off += (size_t)cNT * 128 * 4;   // dedicated
  int* rp = (int*)(w + off); off += (size_t)(F9TOT + 1) * 4;
  off = (off + 7) & ~(size_t)7;
  int2* col = (int2*)(w + off); off += (size_t)ETOT * 8;
  float* F9 = (float*)(w + off); off += (size_t)F9TOT * 9 * 4;   // 13.0 MB
  int* tpv = (int*)(w + off); off += (size_t)cNVOTE * 4;
  if (ws_size < off) return;

  // transients aliased into Sall (dead before first gather use)
  int* deg  = (int*)Sall;
  int* cur  = deg + (F9TOT + 1);
  int* bsum = cur + F9TOT;
  // post-layer aliases: Sall holds hbill_b | CT | KVb | Ql  (66.6 MB <= 92.7)
  ushort* hbill_b = Sall;                                         // 50000*128
  ushort* CT  = Sall + (size_t)cNB * 128;                         // 100000*128
  ushort* KVb = CT + (size_t)cNVOTE * 128;                        // 50000*256
  ushort* Ql  = KVb + (size_t)cNB * 256;                          // 10000*128
  // head scratch aliases Hb (dead after last layer reads it): Uc | Gc
  ushort* Uc = Hb;                                                // 50000*256
  ushort* Gc = Hb + (size_t)50000 * 256;                          // 50000*128

  // relation tables
  const int F9OFF[9] = {0, 50000, 150000, 250000, 260000, 310000, 312000, 312115, 362115};
  const int ESTART[9] = {0, 100000, 200000, 600000, 1000000, 1050000, 1100000, 1150000, 1200000};
  const int SRCT[8] = {1, 0, 2, 1, 3, 0, 0, 4};
  const int* rel_src[8] = {ei_isv, ei_isv + cNBV, ei_vote, ei_vote + cEV,
                           ei_rev, ei_rev + cER, ei_about, ei_about + cNB};
  const int* rel_dst[8] = {ei_isv + cNBV, ei_isv, ei_vote + cEV, ei_vote,
                           ei_rev + cER, ei_rev, ei_about + cNB, ei_about};
  const float* rel_tt[8] = {t_isv, t_isv, t_vote, t_vote, t_rev, t_rev, t_about, t_about};

  // ---- 0. weight conversions ----
  conv_wt<<<dim3(4, 128), 256, 0, stream>>>(pb_W, WT_pb, 770, 128, 800);
  conv_wt<<<dim3(2, 128), 256, 0, stream>>>(pbv_W, WT_pbv, 390, 128, 416);
  conv_wt<<<dim3(1, 128), 256, 0, stream>>>(v_W2, WT_v2, 256, 128, 256);
  conv_wt<<<dim3(1, 128), 256, 0, stream>>>(xq_W, WT_q, 128, 128, 128);
  conv_wt<<<dim3(1, 128), 256, 0, stream>>>(xk_W, WT_kv, 128, 128, 128);
  conv_wt<<<dim3(1, 128), 256, 0, stream>>>(xv_W, WT_kv + 128 * 128, 128, 128, 128);
  conv_head<<<512, 256, 0, stream>>>(v_W1, v_b1, xo_W, xo_b, WH, BH);
  concat_bias2<<<1, 256, 0, stream>>>(xk_b, xv_b, BKV);
  conv_wcat<<<dim3(64, 15), 256, 0, stream>>>(sage_Wl, sage_bl, sage_Wr, sage_br, WC, BC);
  conv_f2b_kernel<<<cdiv(cNT * 128, 256), 256, 0, stream>>>(
      topic_emb, Hb + (size_t)OFFS[4] * 128, cNT * 128);

  // ---- 1. CSR build (fused) ----
  EdgesAll ea;
  for (int r = 0; r < 8; ++r) {
    ea.src[r] = rel_src[r]; ea.dst[r] = rel_dst[r]; ea.f9off[r] = F9OFF[r];
  }
  for (int r = 0; r < 9; ++r) ea.estart[r] = ESTART[r];
  const int nScan = F9TOT + 1;
  const int nb = cdiv(nScan, 1024);
  hipMemsetAsync(deg, 0, (size_t)nScan * sizeof(int), stream);
  hist_all<<<cdiv(ETOT, 256), 256, 0, stream>>>(ea, deg);
  scan_blk<<<nb, 256, 0, stream>>>(deg, rp, bsum, nScan);
  scan_blk<<<1, 256, 0, stream>>>(bsum, bsum, nullptr, nb);
  scan_add<<<nb, 256, 0, stream>>>(rp, bsum, nScan);
  hipMemsetAsync(cur, 0, (size_t)F9TOT * sizeof(int), stream);
  fill_all<<<cdiv(ETOT, 256), 256, 0, stream>>>(ea, rp, cur, col);

  // ---- 1b. F9 precompute (thread-per-node + deterministic topic waves) ----
  F9All fa;
  for (int r = 0; r < 8; ++r) fa.tt[r] = rel_tt[r];
  for (int r = 0; r < 9; ++r) fa.f9off[r] = F9OFF[r];
  f9_thread<<<cdiv(F9TOT, 256), 256, 0, stream>>>(
      fa, col, rp, t2v_w0, t2v_b0, t2v_wk, t2v_bk, F9);
  f9_topic<<<cdiv(cNT * 64, 256), 256, 0, stream>>>(
      col, rp + F9OFF[6], t_about, t2v_w0, t2v_b0, t2v_wk, t2v_bk,
      F9 + (size_t)F9OFF[6] * 9);

  // ---- 2. initial projections (into Hb = layer-0 input) ----
  ProjG pg;
  pg.A[0] = x_bill; pg.Kin[0] = 770; pg.Kp[0] = 800; pg.Wt[0] = WT_pb;
  pg.bias[0] = pb_b; pg.C[0] = Hb + (size_t)OFFS[0] * 128; pg.M[0] = cNB;
  pg.A[1] = x_bv; pg.Kin[1] = 390; pg.Kp[1] = 416; pg.Wt[1] = WT_pbv;
  pg.bias[1] = pbv_b; pg.C[1] = Hb + (size_t)OFFS[1] * 128; pg.M[1] = cNBV;
  pg.blkStart[0] = 0; pg.blkStart[1] = cdiv(cNB, 64);
  pg.blkStart[2] = pg.blkStart[1] + cdiv(cNBV, 64);
  gemm_proj<<<pg.blkStart[2], 256, 0, stream>>>(pg);
  proj_lt_kernel<<<cNLT, 128, 0, stream>>>(x_lt, plt_W1, plt_b1, plt_W2, plt_b2,
                                           Hb + (size_t)OFFS[2] * 128, cNLT);
  proj_comm_kernel<<<cNC, 128, 0, stream>>>(x_comm, pc_W1, pc_b1, pc_W2, pc_b2,
                                            Hb + (size_t)OFFS[3] * 128, cNC);

  // ---- 3. SAGE layers (ping-pong: Hb -> Hh2 -> Hb -> Hh2) ----
  const int KTt[5]   = {512, 384, 256, 256, 256};
  const int TOFFt[5] = {0, 512 * 128, 896 * 128, 1152 * 128, 1408 * 128};
  const int SEGOFF[5][3] = {{0, 260000, 312115}, {50000, 150000, -1},
                            {250000, -1, -1}, {310000, -1, -1}, {312000, -1, -1}};
  ushort* HP[2] = {Hb, Hh2};

  for (int l = 0; l < cLAYERS; ++l) {
    ushort* HCUR = HP[l & 1];
    ushort* HNXT = HP[(l + 1) & 1];

    hipMemsetAsync(SPtop, 0, (size_t)cNT * 128 * sizeof(float), stream);

    GatherAll ga;
    for (int r = 0; r < 8; ++r) ga.Hsrc[r] = HCUR + (size_t)OFFS[SRCT[r]] * 128;
    ga.eW = edge_W; ga.eb = edge_b; ga.col = col; ga.rp = rp; ga.F9 = F9;
    ga.S = Sall; ga.SPtop = SPtop;
    for (int r = 0; r < 7; ++r) ga.f9off[r] = F9OFF[r];
    gather_all<<<cdiv(QW_TOTAL * 16, 256), 256, 0, stream>>>(ga);
    finalize_split<<<cdiv(cNT * 64, 256), 256, 0, stream>>>(
        SPtop, rp + F9OFF[6], F9 + (size_t)F9OFF[6] * 9,
        edge_W + (size_t)6 * 9 * 128, edge_b + (size_t)6 * 128,
        Sall + (size_t)F9OFF[6] * 128, cNT);

    SageG sg;
    sg.blkStart[0] = 0;
    for (int t = 0; t < 5; ++t) {
      sg.M[t] = NSZ[t]; sg.Ktot[t] = KTt[t];
      sg.C[t] = HNXT + (size_t)OFFS[t] * 128;             // ping-pong target
      sg.A[t][0] = HCUR + (size_t)OFFS[t] * 128;
      for (int q = 0; q < 3; ++q)
        sg.A[t][q + 1] = (SEGOFF[t][q] >= 0) ? Sall + (size_t)SEGOFF[t][q] * 128 : nullptr;
      sg.Wt[t] = WC + (size_t)l * (1664 * 128) + TOFFt[t];
      sg.bias[t] = BC + (size_t)(l * 5 + t) * 128;
      sg.lng[t] = ln_g + (size_t)(l * 5 + t) * 128;
      sg.lnb[t] = ln_b + (size_t)(l * 5 + t) * 128;
      sg.blkStart[t + 1] = sg.blkStart[t] + cdiv(NSZ[t], 64);
    }
    gemm_sage<<<sg.blkStart[5], 256, 0, stream>>>(sg);
  }
  ushort* HF = HP[cLAYERS & 1];   // final H (= Hh2 for 3 layers)

  // ---- 4. head ----
  gather_bill<<<cdiv(cNB * 16, 256), 256, 0, stream>>>(
      HF + (size_t)OFFS[1] * 128, col, rp, HF + (size_t)OFFS[0] * 128, hbill_b, cNB);
  gemm_abf<1, false><<<dim3(2, cdiv(cNB, 128)), 256, 0, stream>>>(
      hbill_b, hbill_b, hbill_b, hbill_b, 128, WT_kv, 128, BKV, KVb, 256, cNB);
  gemm_abf<1, false><<<dim3(1, cdiv(cNLT, 128)), 256, 0, stream>>>(
      HF + (size_t)OFFS[2] * 128, nullptr, nullptr, nullptr, 128, WT_q, 128,
      xq_b, Ql, 128, cNLT);
  attn_lite<<<cdiv(cNVOTE * 64, 256), 256, 0, stream>>>(
      Ql, KVb, vote_lt, vote_bv, ei_isv + cNBV, t_for_bill, CT, tpv, cNVOTE);

  const int VCH = 50000;
  for (int v0 = 0; v0 < cNVOTE; v0 += VCH) {
    const int nv = (cNVOTE - v0 < VCH) ? (cNVOTE - v0) : VCH;
    gemm_gat4<true><<<dim3(2, cdiv(nv, 128)), 256, 0, stream>>>(
        HF + (size_t)OFFS[2] * 128, vote_lt + v0,
        HF + (size_t)OFFS[1] * 128, vote_bv + v0,
        HF + (size_t)OFFS[4] * 128, tpv + v0,
        CT + (size_t)v0 * 128,
        WH, BH, Uc, 256, nv);
    gemm_abf<2, false><<<dim3(1, cdiv(nv, 128)), 256, 0, stream>>>(
        Uc, Uc + 128, nullptr, nullptr, 256, WT_v2, 256, v_b2, Gc, 128, nv);
    final_out<<<cdiv(nv, 4), 256, 0, stream>>>(Gc, v_Wo, v_bo, out, v0, nv);
  }
}